// Round 6
// baseline (389.475 us; speedup 1.0000x reference)
//
#include <hip/hip_runtime.h>
#include <math.h>

#define Hd   1024
#define SEQL 2048
#define NB   2
#define NHEADS 16
#define FFND 4096
#define ROWS 4096
#define QKVLD 3072

typedef __attribute__((ext_vector_type(8))) short short8;   // 8 bf16
typedef __attribute__((ext_vector_type(4))) float f32x4;    // MFMA acc

__device__ __forceinline__ unsigned short f2bf(float f) {   // RNE (converts)
  union { float f; unsigned int u; } v; v.f = f;
  return (unsigned short)((v.u + 0x7fffu + ((v.u >> 16) & 1u)) >> 16);
}
__device__ __forceinline__ unsigned short f2bf_fast(float f) {  // round-half-up
  union { float f; unsigned int u; } v; v.f = f;
  return (unsigned short)((v.u + 0x8000u) >> 16);
}
__device__ __forceinline__ float bf2f(unsigned short u) {
  union { unsigned int u; float f; } v; v.u = (unsigned int)u << 16;
  return v.f;
}

// async global->LDS, 16 B/lane; lds dst is wave-uniform base (HW adds lane*16)
__device__ __forceinline__ void gl_lds16(const unsigned short* g,
                                         unsigned short* l) {
  __builtin_amdgcn_global_load_lds(
      (const __attribute__((address_space(1))) void*)g,
      (__attribute__((address_space(3))) void*)l, 16, 0, 0);
}

// ---------------------------------------------------------------------------
// fp32 -> bf16 bulk convert; blocks >= 4096 do the bias concat (merged
// concat3: saves one launch). grid = 4096 + 12.
// ---------------------------------------------------------------------------
__global__ __launch_bounds__(256) void convert_bf16(
    const float* __restrict__ in, unsigned short* __restrict__ out,
    const float* __restrict__ a, const float* __restrict__ b,
    const float* __restrict__ c, float* __restrict__ o) {
  const int bid = blockIdx.x;
  if (bid >= ROWS * Hd / 1024) {
    const int i = (bid - ROWS * Hd / 1024) * 256 + threadIdx.x;
    o[i] = (i < 1024) ? a[i] : (i < 2048 ? b[i - 1024] : c[i - 2048]);
    return;
  }
  const int i = (bid * 256 + threadIdx.x) * 4;
  float4 x = *(const float4*)&in[i];
  ushort4 ov;
  ov.x = f2bf(x.x); ov.y = f2bf(x.y); ov.z = f2bf(x.z); ov.w = f2bf(x.w);
  *(ushort4*)&out[i] = ov;
}

// W[rows][cols] fp32 (ld) -> Wt[cols][rows] bf16 (ldt). grid=(cols/64, rows/64)
__global__ __launch_bounds__(256) void convert_transpose(
    const float* __restrict__ W, int ld,
    unsigned short* __restrict__ Wt, int ldt) {
  __shared__ float T[64][65];
  const int t = threadIdx.x;
  const int c0 = blockIdx.x * 64, r0 = blockIdx.y * 64;
#pragma unroll
  for (int p = 0; p < 4; ++p) {
    const int lin = t + p * 256;
    const int r = lin >> 4, c4 = (lin & 15) * 4;
    float4 x = *(const float4*)&W[(size_t)(r0 + r) * ld + c0 + c4];
    T[r][c4 + 0] = x.x; T[r][c4 + 1] = x.y;
    T[r][c4 + 2] = x.z; T[r][c4 + 3] = x.w;
  }
  __syncthreads();
#pragma unroll
  for (int p = 0; p < 2; ++p) {
    const int lin = t + p * 256;
    const int oc = lin >> 3, ch = (lin & 7) * 8;
    union { unsigned short u[8]; uint4 v; } x;
#pragma unroll
    for (int i = 0; i < 8; ++i) x.u[i] = f2bf(T[ch + i][oc]);
    *(uint4*)&Wt[(size_t)(c0 + oc) * ldt + r0 + ch] = x.v;
  }
}

// 4x 1024x1024 fp32 -> transposed bf16 in one launch. grid=(16,16,4).
__global__ __launch_bounds__(256) void convert_transpose4(
    const float* __restrict__ W0, const float* __restrict__ W1,
    const float* __restrict__ W2, const float* __restrict__ W3,
    unsigned short* __restrict__ T0, unsigned short* __restrict__ T1,
    unsigned short* __restrict__ T2, unsigned short* __restrict__ T3) {
  __shared__ float T[64][65];
  const float* W = (blockIdx.z == 0) ? W0 : (blockIdx.z == 1) ? W1
                 : (blockIdx.z == 2) ? W2 : W3;
  unsigned short* Wt = (blockIdx.z == 0) ? T0 : (blockIdx.z == 1) ? T1
                     : (blockIdx.z == 2) ? T2 : T3;
  const int t = threadIdx.x;
  const int c0 = blockIdx.x * 64, r0 = blockIdx.y * 64;
#pragma unroll
  for (int p = 0; p < 4; ++p) {
    const int lin = t + p * 256;
    const int r = lin >> 4, c4 = (lin & 15) * 4;
    float4 x = *(const float4*)&W[(size_t)(r0 + r) * Hd + c0 + c4];
    T[r][c4 + 0] = x.x; T[r][c4 + 1] = x.y;
    T[r][c4 + 2] = x.z; T[r][c4 + 3] = x.w;
  }
  __syncthreads();
#pragma unroll
  for (int p = 0; p < 2; ++p) {
    const int lin = t + p * 256;
    const int oc = lin >> 3, ch = (lin & 7) * 8;
    union { unsigned short u[8]; uint4 v; } x;
#pragma unroll
    for (int i = 0; i < 8; ++i) x.u[i] = f2bf(T[ch + i][oc]);
    *(uint4*)&Wt[(size_t)(c0 + oc) * Hd + r0 + ch] = x.v;
  }
}

// v-region bf16 [ROWS][QKVLD] -> vt [(b*16+h)*64+d][SEQL]. grid = 32*32
__global__ __launch_bounds__(256) void transpose_v(
    const unsigned short* __restrict__ v, unsigned short* __restrict__ vt) {
  __shared__ unsigned short T[64][72];
  const int t = threadIdx.x;
  const int s0 = (blockIdx.x & 31) * 64;
  const int bh = blockIdx.x >> 5;
  const int b = bh >> 4, h = bh & 15;
#pragma unroll
  for (int p = 0; p < 2; ++p) {
    const int lin = t + p * 256;
    const int r = lin >> 3, c8 = (lin & 7) * 8;
    *(uint4*)&T[r][c8] =
        *(const uint4*)&v[(size_t)(b * SEQL + s0 + r) * QKVLD + h * 64 + c8];
  }
  __syncthreads();
#pragma unroll
  for (int p = 0; p < 2; ++p) {
    const int lin = t + p * 256;
    const int d = lin >> 3, c8 = (lin & 7) * 8;
    union { unsigned short u[8]; uint4 v4; } x;
#pragma unroll
    for (int i = 0; i < 8; ++i) x.u[i] = T[c8 + i][d];
    *(uint4*)&vt[(size_t)(bh * 64 + d) * SEQL + s0 + c8] = x.v4;
  }
}

// ---------------------------------------------------------------------------
// bf16 MFMA GEMM. R15: double-buffered 2-phase (T3 minimum recipe).
// Loop: __syncthreads() [drains own tile-t loads: at that point t+1 is NOT
// yet issued, so the implicit vmcnt(0) IS the counted semantic] -> issue
// tile t+1 DMA into buf^1 -> compute tile t from buf. DMA latency hides
// under a full compute phase; ONE barrier per 64-K step (was 2, with the
// drain immediately after issue = full latency exposed).
// Hazards: buf[nb] last read in compute(t-1), ordered by barrier(t);
// loads(t+1) land before compute(t+1) via barrier(t+1)'s own drain.
// R14's swizzle kept: LDS[r][slot s] = global colblk s^(r&7); reads
// conflict-free (2 lanes/bank). LDS: BN=128 64KB (2 blk/CU), BN=64 48KB (3).
// MODE 0:=+bias 1:relu 2:+= ; OUTBF: bf16 out.
// ---------------------------------------------------------------------------
template <int BN, int MODE, int OUTBF>
__global__ __launch_bounds__(256, (BN == 128 ? 2 : 3)) void gemm_bt(
    const unsigned short* __restrict__ A, int lda,
    const unsigned short* __restrict__ Bt, int ldb,
    const float* __restrict__ bias,
    void* __restrict__ Cv, int ldc, int K) {
  constexpr int NI = (BN == 128) ? 4 : 2;
  constexpr int BG = BN / 32;              // B wave-ops per K-step (2 or 4)
  __shared__ unsigned short As[2][128 * 64];
  __shared__ unsigned short Bs[2][BN * 64];
  const int t = threadIdx.x;
  const int wave = t >> 6, lane = t & 63;
  const int l16 = lane & 15, quad = lane >> 4;
  const int m0 = blockIdx.y * 128, n0 = blockIdx.x * BN;
  const int wm = (wave >> 1) * 64, wn = (wave & 1) * (BN / 2);

  // staging geometry: one wave-op = 64 lanes x 16B = 8 rows x 128B.
  const int lr8 = lane >> 3;                    // 0..7 local row
  const int sc8 = 8 * ((lane & 7) ^ lr8);       // pre-swizzled source slot

  f32x4 acc[4][NI];
#pragma unroll
  for (int i = 0; i < 4; ++i)
#pragma unroll
    for (int j = 0; j < NI; ++j) acc[i][j] = (f32x4){0.f, 0.f, 0.f, 0.f};

  const unsigned short* Apg[4];
  int lAo[4];
#pragma unroll
  for (int j = 0; j < 4; ++j) {
    const int r0 = (wave + 4 * j) * 8;
    Apg[j] = &A[(size_t)(m0 + r0 + lr8) * lda + sc8];
    lAo[j] = r0 * 64;
  }
  const unsigned short* Bpg[BG];
  int lBo[BG];
#pragma unroll
  for (int j = 0; j < BG; ++j) {
    const int r0 = (wave + 4 * j) * 8;
    Bpg[j] = &Bt[(size_t)(n0 + r0 + lr8) * ldb + sc8];
    lBo[j] = r0 * 64;
  }

  const int NT = K >> 6;

  // prologue: tile 0 -> buf 0
#pragma unroll
  for (int j = 0; j < 4; ++j) gl_lds16(Apg[j], &As[0][lAo[j]]);
#pragma unroll
  for (int j = 0; j < BG; ++j) gl_lds16(Bpg[j], &Bs[0][lBo[j]]);

  for (int tk = 0; tk < NT; ++tk) {
    const int cb = tk & 1, nb = cb ^ 1;
    __syncthreads();   // drain own tile-tk loads + sync all waves

    if (tk + 1 < NT) {
      const int k1 = (tk + 1) << 6;
#pragma unroll
      for (int j = 0; j < 4; ++j) gl_lds16(Apg[j] + k1, &As[nb][lAo[j]]);
#pragma unroll
      for (int j = 0; j < BG; ++j) gl_lds16(Bpg[j] + k1, &Bs[nb][lBo[j]]);
    }

#pragma unroll
    for (int kh = 0; kh < 2; ++kh) {
      short8 af[4], bfr[NI];
#pragma unroll
      for (int mi = 0; mi < 4; ++mi) {
        const int r = wm + mi * 16 + l16;
        af[mi] = *(const short8*)&As[cb][r * 64 + (((quad + 4 * kh) ^ (r & 7)) * 8)];
      }
#pragma unroll
      for (int ni = 0; ni < NI; ++ni) {
        const int r = wn + ni * 16 + l16;
        bfr[ni] = *(const short8*)&Bs[cb][r * 64 + (((quad + 4 * kh) ^ (r & 7)) * 8)];
      }
#pragma unroll
      for (int mi = 0; mi < 4; ++mi)
#pragma unroll
        for (int ni = 0; ni < NI; ++ni)
          acc[mi][ni] = __builtin_amdgcn_mfma_f32_16x16x32_bf16(
              af[mi], bfr[ni], acc[mi][ni], 0, 0, 0);
    }
    // no trailing barrier: next iteration's __syncthreads() orders
    // compute(tk) before loads(tk+2) overwrite buf[cb].
  }

#pragma unroll
  for (int mi = 0; mi < 4; ++mi) {
#pragma unroll
    for (int ni = 0; ni < NI; ++ni) {
      const int col = n0 + wn + ni * 16 + l16;
      const float bv = (MODE == 2) ? 0.0f : bias[col];
#pragma unroll
      for (int r = 0; r < 4; ++r) {
        const int row = m0 + wm + mi * 16 + quad * 4 + r;
        float v = acc[mi][ni][r] + bv;
        if (MODE == 1) v = fmaxf(v, 0.0f);
        if (OUTBF) {
          ((unsigned short*)Cv)[(size_t)row * ldc + col] = f2bf_fast(v);
        } else {
          float* Cf = (float*)Cv;
          if (MODE == 2) Cf[(size_t)row * ldc + col] += v;
          else           Cf[(size_t)row * ldc + col] = v;
        }
      }
    }
  }
}

// ---------------------------------------------------------------------------
// MFMA flash attention, split-j (2 halves, grid 2048), no-max softmax.
// Exact R9 body (best measured: 77.4-79.4us). Untouched this round.
// ---------------------------------------------------------------------------
__global__ __launch_bounds__(256, 5) void attn_mfma(
    const unsigned short* __restrict__ Q,
    const unsigned short* __restrict__ K,
    const unsigned short* __restrict__ Vt,
    const int* __restrict__ mask,
    unsigned short* __restrict__ Op,    // [2][ROWS][Hd] bf16 partials
    float* __restrict__ ls) {           // [2][NB][NHEADS][SEQL]
  __shared__ unsigned short Qs[64 * 72];   // reused as Ps after frag hoist
  __shared__ unsigned short Ks[64 * 72];
  __shared__ unsigned short Vs[64 * 72];
  unsigned short* Ps = Qs;

  const int t = threadIdx.x;
  const int wave = t >> 6, lane = t & 63;
  const int l16 = lane & 15, quad = lane >> 4;
  const int qb = blockIdx.x & 31;
  const int h  = (blockIdx.x >> 5) & 15;
  const int b  = (blockIdx.x >> 9) & 1;
  const int jh = blockIdx.x >> 10;
  const int q0 = qb * 64;
  const int bh = b * NHEADS + h;
  const int jbeg = jh * (SEQL / 2), jend = jbeg + SEQL / 2;
  const float NEGINF = -__builtin_inff();

  const int lr = t >> 3, lc8 = (t & 7) * 8;   // staging coords
  const unsigned short* Kbase = &K[(size_t)(b * SEQL + lr) * QKVLD + h * 64 + lc8];
  const unsigned short* Vbase = &Vt[(size_t)(bh * 64 + lr) * SEQL + lc8];
  const size_t Krow32 = (size_t)32 * QKVLD;   // +32 rows

#pragma unroll
  for (int p = 0; p < 2; ++p) {
    const int r = lr + p * 32;
    *(uint4*)&Qs[r * 72 + lc8] =
        *(const uint4*)&Q[(size_t)(b * SEQL + q0 + r) * QKVLD + h * 64 + lc8];
  }
  __syncthreads();
  const short8 aq0 = *(const short8*)&Qs[(wave * 16 + l16) * 72 + quad * 8];
  const short8 aq1 = *(const short8*)&Qs[(wave * 16 + l16) * 72 + 32 + quad * 8];

  float lrow[4] = {0.f, 0.f, 0.f, 0.f};
  f32x4 accO[4];
#pragma unroll
  for (int nd = 0; nd < 4; ++nd) accO[nd] = (f32x4){0.f, 0.f, 0.f, 0.f};

  // preload tile jbeg
  uint4 kv0 = *(const uint4*)(Kbase + (size_t)jbeg * QKVLD);
  uint4 kv1 = *(const uint4*)(Kbase + (size_t)jbeg * QKVLD + Krow32);
  uint4 vv0 = *(const uint4*)(Vbase + jbeg);
  uint4 vv1 = *(const uint4*)(Vbase + jbeg + 32 * SEQL);

  for (int j0 = jbeg; j0 < jend; j0 += 64) {
    __syncthreads();   // prior compute's LDS reads done (iter0: Q frag reads)
    *(uint4*)&Ks[lr * 72 + lc8] = kv0;
    *(uint4*)&Ks[(lr + 32) * 72 + lc8] = kv1;
    *(uint4*)&Vs[lr * 72 + lc8] = vv0;
    *(uint4*)&Vs[(lr + 32) * 72 + lc8] = vv1;
    __syncthreads();

    // prefetch next tile (issued early; consumed after next barrier)
    if (j0 + 64 < jend) {
      const unsigned short* kp = Kbase + (size_t)(j0 + 64) * QKVLD;
      const unsigned short* vp = Vbase + (j0 + 64);
      kv0 = *(const uint4*)(kp);
      kv1 = *(const uint4*)(kp + Krow32);
      vv0 = *(const uint4*)(vp);
      vv1 = *(const uint4*)(vp + 32 * SEQL);
    }

    // per 16x16 tile: S -> mask -> exp -> row-sum -> pack to LDS (short-lived)
#pragma unroll
    for (int nt = 0; nt < 4; ++nt) {
      short8 bk0 = *(const short8*)&Ks[(nt * 16 + l16) * 72 + quad * 8];
      short8 bk1 = *(const short8*)&Ks[(nt * 16 + l16) * 72 + 32 + quad * 8];
      f32x4 z = (f32x4){0.f, 0.f, 0.f, 0.f};
      z = __builtin_amdgcn_mfma_f32_16x16x32_bf16(aq0, bk0, z, 0, 0, 0);
      z = __builtin_amdgcn_mfma_f32_16x16x32_bf16(aq1, bk1, z, 0, 0, 0);
      const bool ok = mask[b * SEQL + j0 + nt * 16 + l16] != 0;
      unsigned short pk[4];
#pragma unroll
      for (int r = 0; r < 4; ++r) {
        const float x = ok ? z[r] * (1.0f / 1024.0f) : NEGINF;
        const float p = __expf(x);
        lrow[r] += p;
        pk[r] = f2bf_fast(p);
      }
#pragma unroll
      for (int r = 0; r < 4; ++r)
        Ps[(wave * 16 + quad * 4 + r) * 72 + nt * 16 + l16] = pk[r];
    }

    // O += P V   (Ps written/read by the same wave)
    short8 ap0 = *(const short8*)&Ps[(wave * 16 + l16) * 72 + quad * 8];
    short8 ap1 = *(const short8*)&Ps[(wave * 16 + l16) * 72 + 32 + quad * 8];
#pragma unroll
    for (int nd = 0; nd < 4; ++nd) {
      short8 bv0 = *(const short8*)&Vs[(nd * 16 + l16) * 72 + quad * 8];
      short8 bv1 = *(const short8*)&Vs[(nd * 16 + l16) * 72 + 32 + quad * 8];
      accO[nd] = __builtin_amdgcn_mfma_f32_16x16x32_bf16(ap0, bv0, accO[nd], 0, 0, 0);
      accO[nd] = __builtin_amdgcn_mfma_f32_16x16x32_bf16(ap1, bv1, accO[nd], 0, 0, 0);
    }
  }

  // final 16-lane row-sum reduction; store l (no normalization here)
#pragma unroll
  for (int r = 0; r < 4; ++r) {
#pragma unroll
    for (int off = 1; off < 16; off <<= 1)
      lrow[r] += __shfl_xor(lrow[r], off, 64);
  }
  if (l16 == 0) {
#pragma unroll
    for (int r = 0; r < 4; ++r)
      ls[((size_t)(jh * NB + b) * NHEADS + h) * SEQL + q0 + wave * 16 +
         quad * 4 + r] = lrow[r];
  }
#pragma unroll
  for (int nd = 0; nd < 4; ++nd)
#pragma unroll
    for (int r = 0; r < 4; ++r) {
      const int rowg = b * SEQL + q0 + wave * 16 + quad * 4 + r;
      Op[(size_t)jh * ROWS * Hd + (size_t)rowg * Hd + h * 64 + nd * 16 + l16] =
          f2bf_fast(accO[nd][r]);
    }
}

// ---------------------------------------------------------------------------
// ctx = (O0 + O1) / (l0 + l1). grid = ROWS, 256 thr x 4 cols.
// ---------------------------------------------------------------------------
__global__ __launch_bounds__(256) void attn_combine(
    const unsigned short* __restrict__ Op, const float* __restrict__ ls,
    unsigned short* __restrict__ ctxb) {
  const int row = blockIdx.x;
  const int b = row >> 11, q = row & (SEQL - 1);
  const int t = threadIdx.x;
  const int c0 = t * 4, h = t >> 4;
  const float l0 = ls[((size_t)(b)*NHEADS + h) * SEQL + q];
  const float l1 = ls[((size_t)(NB + b) * NHEADS + h) * SEQL + q];
  const float inv = 1.0f / (l0 + l1);
  ushort4 a = *(const ushort4*)&Op[(size_t)row * Hd + c0];
  ushort4 c = *(const ushort4*)&Op[(size_t)ROWS * Hd + (size_t)row * Hd + c0];
  ushort4 o;
  o.x = f2bf_fast((bf2f(a.x) + bf2f(c.x)) * inv);
  o.y = f2bf_fast((bf2f(a.y) + bf2f(c.y)) * inv);
  o.z = f2bf_fast((bf2f(a.z) + bf2f(c.z)) * inv);
  o.w = f2bf_fast((bf2f(a.w) + bf2f(c.w)) * inv);
  *(ushort4*)&ctxb[(size_t)row * Hd + c0] = o;
}

// ---------------------------------------------------------------------------
// out = LayerNorm(A + R)*g + b. ABF: A is bf16 (else fp32). In-place safe.
// ---------------------------------------------------------------------------
template <int ABF>
__global__ __launch_bounds__(256) void add_ln_kernel(
    const void* Av, const float* R,
    const float* __restrict__ gamma, const float* __restrict__ beta,
    float* out, unsigned short* outb) {
  const int row = blockIdx.x;
  const int t = threadIdx.x;
  const size_t baser = (size_t)row * Hd;

  float a0, a1, a2, a3;
  if (ABF) {
    ushort4 a = *(const ushort4*)&((const unsigned short*)Av)[baser + t * 4];
    a0 = bf2f(a.x); a1 = bf2f(a.y); a2 = bf2f(a.z); a3 = bf2f(a.w);
  } else {
    float4 a = *(const float4*)&((const float*)Av)[baser + t * 4];
    a0 = a.x; a1 = a.y; a2 = a.z; a3 = a.w;
  }
  float4 r = *(const float4*)&R[baser + t * 4];
  float x0 = a0 + r.x, x1 = a1 + r.y, x2 = a2 + r.z, x3 = a3 + r.w;
  float s  = x0 + x1 + x2 + x3;
  float ss = x0 * x0 + x1 * x1 + x2 * x2 + x3 * x3;

#pragma unroll
  for (int off = 32; off > 0; off >>= 1) {
    s  += __shfl_down(s, off, 64);
    ss += __shfl_down(ss, off, 64);
  }

  __shared__ float rs[4], rss[4];
  __shared__ float sh_mean, sh_rstd;
  if ((t & 63) == 0) { rs[t >> 6] = s; rss[t >> 6] = ss; }
  __syncthreads();
  if (t == 0) {
    const float S  = rs[0] + rs[1] + rs[2] + rs[3];
    const float SS = rss[0] + rss[1] + rss[2] + rss[3];
    const float mean = S * (1.0f / Hd);
    const float var  = SS * (1.0f / Hd) - mean * mean;
    sh_mean = mean;
    sh_rstd = rsqrtf(var + 1e-5f);
  }
  __syncthreads();
  const float mean = sh_mean, rstd = sh_rstd;

  float4 gm = *(const float4*)&gamma[t * 4];
  float4 bt = *(const float4*)&beta[t * 4];
  float4 o;
  o.x = (x0 - mean) * rstd * gm.x + bt.x;
  o.y = (x1 - mean) * rstd * gm.y + bt.y;
  o.z = (x2 - mean) * rstd * gm.z + bt.z;
  o.w = (x3 - mean) * rstd * gm.w + bt.w;
  *(float4*)&out[baser + t * 4] = o;
  if (outb) {
    ushort4 ob;
    ob.x = f2bf(o.x); ob.y = f2bf(o.y); ob.z = f2bf(o.z); ob.w = f2bf(o.w);
    *(ushort4*)&outb[baser + t * 4] = ob;
  }
}

// ---------------------------------------------------------------------------
// ws (48MB): P1: 0-8 srcb | 8-14 WqkvT | 14 bqkv | 16-40 qkv | 40-48 vt.
// attn: Opart 0-16 (srcb/WqkvT dead). d_out: ls +8, WoT +9-11, ctxb 0-8.
// Wo-gemm -> mhsa ws 16-32. LN1 -> x1 fp32 = d_out 0-16 (ctxb/ls/WoT dead),
// x1b ws 8-16. W1T full ws 0-8 -> FFN1 -> hb ws 16-48 (32MB). W2T full
// ws 0-8 -> FFN2 K=4096 -> f2b bf16 ws 8-16 (x1b dead). LN2(f2b, x1) ->
// d_out in-place.
// ---------------------------------------------------------------------------
extern "C" void kernel_launch(void* const* d_in, const int* in_sizes, int n_in,
                              void* d_out, int out_size, void* d_ws, size_t ws_size,
                              hipStream_t stream) {
  const float* src  = (const float*)d_in[0];
  const int*   kmsk = (const int*)  d_in[1];
  const float* Wq   = (const float*)d_in[2];
  const float* bq   = (const float*)d_in[3];
  const float* Wk   = (const float*)d_in[4];
  const float* bk   = (const float*)d_in[5];
  const float* Wv   = (const float*)d_in[6];
  const float* bv   = (const float*)d_in[7];
  const float* Wo   = (const float*)d_in[8];
  const float* bo   = (const float*)d_in[9];
  const float* ln1g = (const float*)d_in[10];
  const float* ln1b = (const float*)d_in[11];
  const float* W1   = (const float*)d_in[12];
  const float* b1   = (const float*)d_in[13];
  const float* W2   = (const float*)d_in[14];
  const float* b2   = (const float*)d_in[15];
  const float* ln2g = (const float*)d_in[16];
  const float* ln2b = (const float*)d_in[17];

  char* w8 = (char*)d_ws;
  char* o8 = (char*)d_out;
  const size_t MB = 1024 * 1024;
  unsigned short* srcb  = (unsigned short*)(w8 + 0 * MB);
  unsigned short* WqkvT = (unsigned short*)(w8 + 8 * MB);
  float*          bqkv  = (float*)(w8 + 14 * MB);
  unsigned short* qkv   = (unsigned short*)(w8 + 16 * MB);
  unsigned short* vt    = (unsigned short*)(w8 + 40 * MB);
  unsigned short* Opart = (unsigned short*)(w8 + 0 * MB);   // 16 MB
  float*          ls    = (float*)(o8 + 8 * MB);            // 512 KB
  unsigned short* WoT   = (unsigned short*)(o8 + 9 * MB);   // 2 MB
  unsigned short* ctxb  = (unsigned short*)d_out;           // 8 MB
  float*          mhsa  = (float*)(w8 + 16 * MB);           // 16 MB
  float*          x1    = (float*)d_out;                    // 16 MB fp32
  unsigned short* x1b   = (unsigned short*)(w8 + 8 * MB);   // 8 MB
  unsigned short* W1T   = (unsigned short*)(w8 + 0 * MB);   // 8 MB full
  unsigned short* hb    = (unsigned short*)(w8 + 16 * MB);  // 32 MB full
  unsigned short* W2T   = (unsigned short*)(w8 + 0 * MB);   // 8 MB full
  unsigned short* f2b   = (unsigned short*)(w8 + 8 * MB);   // 8 MB

  dim3 blk(256);

  convert_bf16<<<ROWS * Hd / 1024 + 12, blk, 0, stream>>>(
      src, srcb, bq, bk, bv, bqkv);
  convert_transpose4<<<dim3(16, 16, 4), blk, 0, stream>>>(
      Wq, Wk, Wv, Wo, WqkvT, WqkvT + 1024 * 1024, WqkvT + 2 * 1024 * 1024, WoT);

  // fused QKV: [4096][3072] = srcb @ WqkvT^T  (BK=64 dbuf, grid 24x32)
  gemm_bt<128, 0, 1><<<dim3(QKVLD / 128, ROWS / 128), blk, 0, stream>>>(
      srcb, Hd, WqkvT, Hd, bqkv, qkv, QKVLD, Hd);

  transpose_v<<<1024, blk, 0, stream>>>(qkv + 2048, vt);
  attn_mfma<<<2048, blk, 0, stream>>>(qkv, qkv + 1024, vt, kmsk, Opart, ls);
  attn_combine<<<ROWS, blk, 0, stream>>>(Opart, ls, ctxb);

  gemm_bt<64, 0, 0><<<dim3(Hd / 64, ROWS / 128), blk, 0, stream>>>(
      ctxb, Hd, WoT, Hd, bo, mhsa, Hd, Hd);

  add_ln_kernel<0><<<ROWS, blk, 0, stream>>>(mhsa, src, ln1g, ln1b, x1, x1b);

  // FFN single-pass: W1T [4096][1024], hb [4096][4096] bf16, W2T [1024][4096]
  convert_transpose<<<dim3(64, 16), blk, 0, stream>>>(W1, FFND, W1T, Hd);
  gemm_bt<128, 1, 1><<<dim3(FFND / 128, ROWS / 128), blk, 0, stream>>>(
      x1b, Hd, W1T, Hd, b1, hb, FFND, Hd);
  convert_transpose<<<dim3(16, 64), blk, 0, stream>>>(W2, Hd, W2T, FFND);
  gemm_bt<64, 0, 1><<<dim3(Hd / 64, ROWS / 128), blk, 0, stream>>>(
      hb, FFND, W2T, FFND, b2, f2b, Hd, FFND);

  add_ln_kernel<1><<<ROWS, blk, 0, stream>>>(f2b, x1, ln2g, ln2b,
                                             (float*)d_out, nullptr);
}

// Round 7
// 378.617 us; speedup vs baseline: 1.0287x; 1.0287x over previous
//
#include <hip/hip_runtime.h>
#include <math.h>

#define Hd   1024
#define SEQL 2048
#define NB   2
#define NHEADS 16
#define FFND 4096
#define ROWS 4096
#define QKVLD 3072

typedef __attribute__((ext_vector_type(8))) short short8;    // 8 bf16
typedef __attribute__((ext_vector_type(4))) float f32x4;     // 16x16 acc
typedef __attribute__((ext_vector_type(16))) float f32x16;   // 32x32 acc

__device__ __forceinline__ unsigned short f2bf(float f) {   // RNE (converts)
  union { float f; unsigned int u; } v; v.f = f;
  return (unsigned short)((v.u + 0x7fffu + ((v.u >> 16) & 1u)) >> 16);
}
__device__ __forceinline__ unsigned short f2bf_fast(float f) {  // round-half-up
  union { float f; unsigned int u; } v; v.f = f;
  return (unsigned short)((v.u + 0x8000u) >> 16);
}
__device__ __forceinline__ float bf2f(unsigned short u) {
  union { unsigned int u; float f; } v; v.u = (unsigned int)u << 16;
  return v.f;
}
// pack two f32 -> 2 bf16 in one dword (lo = a, hi = b); no builtin (m240)
__device__ __forceinline__ int cvtpk(float a, float b) {
  int d;
  asm("v_cvt_pk_bf16_f32 %0, %1, %2" : "=v"(d) : "v"(a), "v"(b));
  return d;
}
// swap a's lanes 32-63 with b's lanes 0-31 (pure VALU, no mem ordering issues)
__device__ __forceinline__ void pswap(int& a, int& b) {
  asm("v_permlane32_swap_b32 %0, %1" : "+v"(a), "+v"(b));
}

// async global->LDS, 16 B/lane; lds dst is wave-uniform base (HW adds lane*16)
__device__ __forceinline__ void gl_lds16(const unsigned short* g,
                                         unsigned short* l) {
  __builtin_amdgcn_global_load_lds(
      (const __attribute__((address_space(1))) void*)g,
      (__attribute__((address_space(3))) void*)l, 16, 0, 0);
}

// ---------------------------------------------------------------------------
// fp32 -> bf16 bulk convert; blocks >= 4096 do the bias concat. grid = 4096+12.
// ---------------------------------------------------------------------------
__global__ __launch_bounds__(256) void convert_bf16(
    const float* __restrict__ in, unsigned short* __restrict__ out,
    const float* __restrict__ a, const float* __restrict__ b,
    const float* __restrict__ c, float* __restrict__ o) {
  const int bid = blockIdx.x;
  if (bid >= ROWS * Hd / 1024) {
    const int i = (bid - ROWS * Hd / 1024) * 256 + threadIdx.x;
    o[i] = (i < 1024) ? a[i] : (i < 2048 ? b[i - 1024] : c[i - 2048]);
    return;
  }
  const int i = (bid * 256 + threadIdx.x) * 4;
  float4 x = *(const float4*)&in[i];
  ushort4 ov;
  ov.x = f2bf(x.x); ov.y = f2bf(x.y); ov.z = f2bf(x.z); ov.w = f2bf(x.w);
  *(ushort4*)&out[i] = ov;
}

// W[rows][cols] fp32 (ld) -> Wt[cols][rows] bf16 (ldt). grid=(cols/64, rows/64)
__global__ __launch_bounds__(256) void convert_transpose(
    const float* __restrict__ W, int ld,
    unsigned short* __restrict__ Wt, int ldt) {
  __shared__ float T[64][65];
  const int t = threadIdx.x;
  const int c0 = blockIdx.x * 64, r0 = blockIdx.y * 64;
#pragma unroll
  for (int p = 0; p < 4; ++p) {
    const int lin = t + p * 256;
    const int r = lin >> 4, c4 = (lin & 15) * 4;
    float4 x = *(const float4*)&W[(size_t)(r0 + r) * ld + c0 + c4];
    T[r][c4 + 0] = x.x; T[r][c4 + 1] = x.y;
    T[r][c4 + 2] = x.z; T[r][c4 + 3] = x.w;
  }
  __syncthreads();
#pragma unroll
  for (int p = 0; p < 2; ++p) {
    const int lin = t + p * 256;
    const int oc = lin >> 3, ch = (lin & 7) * 8;
    union { unsigned short u[8]; uint4 v; } x;
#pragma unroll
    for (int i = 0; i < 8; ++i) x.u[i] = f2bf(T[ch + i][oc]);
    *(uint4*)&Wt[(size_t)(c0 + oc) * ldt + r0 + ch] = x.v;
  }
}

// 4x 1024x1024 fp32 -> transposed bf16 in one launch. grid=(16,16,4).
__global__ __launch_bounds__(256) void convert_transpose4(
    const float* __restrict__ W0, const float* __restrict__ W1,
    const float* __restrict__ W2, const float* __restrict__ W3,
    unsigned short* __restrict__ T0, unsigned short* __restrict__ T1,
    unsigned short* __restrict__ T2, unsigned short* __restrict__ T3) {
  __shared__ float T[64][65];
  const float* W = (blockIdx.z == 0) ? W0 : (blockIdx.z == 1) ? W1
                 : (blockIdx.z == 2) ? W2 : W3;
  unsigned short* Wt = (blockIdx.z == 0) ? T0 : (blockIdx.z == 1) ? T1
                     : (blockIdx.z == 2) ? T2 : T3;
  const int t = threadIdx.x;
  const int c0 = blockIdx.x * 64, r0 = blockIdx.y * 64;
#pragma unroll
  for (int p = 0; p < 4; ++p) {
    const int lin = t + p * 256;
    const int r = lin >> 4, c4 = (lin & 15) * 4;
    float4 x = *(const float4*)&W[(size_t)(r0 + r) * Hd + c0 + c4];
    T[r][c4 + 0] = x.x; T[r][c4 + 1] = x.y;
    T[r][c4 + 2] = x.z; T[r][c4 + 3] = x.w;
  }
  __syncthreads();
#pragma unroll
  for (int p = 0; p < 2; ++p) {
    const int lin = t + p * 256;
    const int oc = lin >> 3, ch = (lin & 7) * 8;
    union { unsigned short u[8]; uint4 v; } x;
#pragma unroll
    for (int i = 0; i < 8; ++i) x.u[i] = f2bf(T[ch + i][oc]);
    *(uint4*)&Wt[(size_t)(c0 + oc) * Hd + r0 + ch] = x.v;
  }
}

// v-region bf16 [ROWS][QKVLD] -> vt [(b*16+h)*64+d][SEQL]. grid = 32*32
__global__ __launch_bounds__(256) void transpose_v(
    const unsigned short* __restrict__ v, unsigned short* __restrict__ vt) {
  __shared__ unsigned short T[64][72];
  const int t = threadIdx.x;
  const int s0 = (blockIdx.x & 31) * 64;
  const int bh = blockIdx.x >> 5;
  const int b = bh >> 4, h = bh & 15;
#pragma unroll
  for (int p = 0; p < 2; ++p) {
    const int lin = t + p * 256;
    const int r = lin >> 3, c8 = (lin & 7) * 8;
    *(uint4*)&T[r][c8] =
        *(const uint4*)&v[(size_t)(b * SEQL + s0 + r) * QKVLD + h * 64 + c8];
  }
  __syncthreads();
#pragma unroll
  for (int p = 0; p < 2; ++p) {
    const int lin = t + p * 256;
    const int d = lin >> 3, c8 = (lin & 7) * 8;
    union { unsigned short u[8]; uint4 v4; } x;
#pragma unroll
    for (int i = 0; i < 8; ++i) x.u[i] = T[c8 + i][d];
    *(uint4*)&vt[(size_t)(bh * 64 + d) * SEQL + s0 + c8] = x.v4;
  }
}

// ---------------------------------------------------------------------------
// bf16 MFMA GEMM, R14 config (best measured): BK=64 single-buffer, XOR
// swizzle (conflict-free ds_read_b128 at 128B rows), 2 barriers per 64-K.
// R15's explicit dbuf was neutral (m99 mechanism: cross-block overlap
// already hides DMA latency) -> reverted. MODE 0:=+bias 1:relu 2:+= .
// ---------------------------------------------------------------------------
template <int BN, int MODE, int OUTBF>
__global__ __launch_bounds__(256, (BN == 128 ? 3 : 4)) void gemm_bt(
    const unsigned short* __restrict__ A, int lda,
    const unsigned short* __restrict__ Bt, int ldb,
    const float* __restrict__ bias,
    void* __restrict__ Cv, int ldc, int K) {
  constexpr int NI = (BN == 128) ? 4 : 2;
  constexpr int BG = BN / 32;              // B wave-ops per K-step (2 or 4)
  __shared__ unsigned short As[128 * 64];
  __shared__ unsigned short Bs[BN * 64];
  const int t = threadIdx.x;
  const int wave = t >> 6, lane = t & 63;
  const int l16 = lane & 15, quad = lane >> 4;
  const int m0 = blockIdx.y * 128, n0 = blockIdx.x * BN;
  const int wm = (wave >> 1) * 64, wn = (wave & 1) * (BN / 2);

  const int lr8 = lane >> 3;                    // 0..7 local row
  const int sc8 = 8 * ((lane & 7) ^ lr8);       // pre-swizzled source slot

  f32x4 acc[4][NI];
#pragma unroll
  for (int i = 0; i < 4; ++i)
#pragma unroll
    for (int j = 0; j < NI; ++j) acc[i][j] = (f32x4){0.f, 0.f, 0.f, 0.f};

  const unsigned short* Apg[4];
  unsigned short* lAg[4];
#pragma unroll
  for (int j = 0; j < 4; ++j) {
    const int r0 = (wave + 4 * j) * 8;
    Apg[j] = &A[(size_t)(m0 + r0 + lr8) * lda + sc8];
    lAg[j] = &As[r0 * 64];
  }
  const unsigned short* Bpg[BG];
  unsigned short* lBg[BG];
#pragma unroll
  for (int j = 0; j < BG; ++j) {
    const int r0 = (wave + 4 * j) * 8;
    Bpg[j] = &Bt[(size_t)(n0 + r0 + lr8) * ldb + sc8];
    lBg[j] = &Bs[r0 * 64];
  }

  for (int k0 = 0; k0 < K; k0 += 64) {
#pragma unroll
    for (int j = 0; j < 4; ++j) gl_lds16(Apg[j] + k0, lAg[j]);
#pragma unroll
    for (int j = 0; j < BG; ++j) gl_lds16(Bpg[j] + k0, lBg[j]);
    __syncthreads();   // drains vmcnt -> staging visible

#pragma unroll
    for (int kh = 0; kh < 2; ++kh) {
      short8 af[4], bfr[NI];
#pragma unroll
      for (int mi = 0; mi < 4; ++mi) {
        const int r = wm + mi * 16 + l16;
        af[mi] = *(const short8*)&As[r * 64 + (((quad + 4 * kh) ^ (r & 7)) * 8)];
      }
#pragma unroll
      for (int ni = 0; ni < NI; ++ni) {
        const int r = wn + ni * 16 + l16;
        bfr[ni] = *(const short8*)&Bs[r * 64 + (((quad + 4 * kh) ^ (r & 7)) * 8)];
      }
#pragma unroll
      for (int mi = 0; mi < 4; ++mi)
#pragma unroll
        for (int ni = 0; ni < NI; ++ni)
          acc[mi][ni] = __builtin_amdgcn_mfma_f32_16x16x32_bf16(
              af[mi], bfr[ni], acc[mi][ni], 0, 0, 0);
    }
    __syncthreads();   // all frag reads done before next DMA lands
  }

#pragma unroll
  for (int mi = 0; mi < 4; ++mi) {
#pragma unroll
    for (int ni = 0; ni < NI; ++ni) {
      const int col = n0 + wn + ni * 16 + l16;
      const float bv = (MODE == 2) ? 0.0f : bias[col];
#pragma unroll
      for (int r = 0; r < 4; ++r) {
        const int row = m0 + wm + mi * 16 + quad * 4 + r;
        float v = acc[mi][ni][r] + bv;
        if (MODE == 1) v = fmaxf(v, 0.0f);
        if (OUTBF) {
          ((unsigned short*)Cv)[(size_t)row * ldc + col] = f2bf_fast(v);
        } else {
          float* Cf = (float*)Cv;
          if (MODE == 2) Cf[(size_t)row * ldc + col] += v;
          else           Cf[(size_t)row * ldc + col] = v;
        }
      }
    }
  }
}

// ---------------------------------------------------------------------------
// R16: MFMA flash attention, 32x32 + in-register softmax (T12 port).
// Block = 128 q, 4 waves x 32 q; split-j (jh=2); grid 1024, all co-resident
// at 4 blocks/CU (LDS 18.4KB, VGPR capped 128 via launch_bounds(256,4)).
//  * swapped QK^T: z = mfma_32x32x16(A=K_frag, B=Q_frag) -> C[j][q], q = l&31
//    lane-local, j rows = (reg&3)+8*(reg>>2)+4*(l>>5) (m74/m101 layout).
//  * P stays in registers: 8 cvt_pk + 4 permlane32_swap per 32-j subtile
//    rebuild the PV A-frags exactly (swap(pk0,pk2) -> frag dw0 + dw2 in one
//    op). No Ps LDS, no lgkm stall, no bpermute.
//  * row-sum: local adds + ONE shfl_xor(32) (lanes l, l+32 share q).
//  * K/V staging identical to R9 (Ks=[j][d], Vs=[d][j], pitch 72 — b128
//    frag reads at 32 rows x 2 col-groups hit the 8-access/bank floor).
// ---------------------------------------------------------------------------
__global__ __launch_bounds__(256, 4) void attn_mfma(
    const unsigned short* __restrict__ Q,
    const unsigned short* __restrict__ K,
    const unsigned short* __restrict__ Vt,
    const int* __restrict__ mask,
    unsigned short* __restrict__ Op,    // [2][ROWS][Hd] bf16 partials
    float* __restrict__ ls) {           // [2][NB][NHEADS][SEQL]
  __shared__ unsigned short Ks[64 * 72];   // [j][d]
  __shared__ unsigned short Vs[64 * 72];   // [d][j]

  const int t = threadIdx.x;
  const int wave = t >> 6, lane = t & 63;
  const int l32 = lane & 31, hi = lane >> 5;
  const int qb = blockIdx.x & 15;
  const int h  = (blockIdx.x >> 4) & 15;
  const int b  = (blockIdx.x >> 8) & 1;
  const int jh = blockIdx.x >> 9;
  const int q0 = qb * 128;
  const int bh = b * NHEADS + h;
  const int jbeg = jh * (SEQL / 2), jend = jbeg + SEQL / 2;
  const float NEGINF = -__builtin_inff();

  const int lr = t >> 3, lc8 = (t & 7) * 8;   // staging coords
  const unsigned short* Kbase = &K[(size_t)(b * SEQL + lr) * QKVLD + h * 64 + lc8];
  const unsigned short* Vbase = &Vt[(size_t)(bh * 64 + lr) * SEQL + lc8];
  const size_t Krow32 = (size_t)32 * QKVLD;   // +32 rows

  // Q as B-frags, straight from global: B[k=d][col=q], lane: q=l32, d=ks*16+hi*8+e
  const unsigned short* Qrow =
      &Q[(size_t)(b * SEQL + q0 + wave * 32 + l32) * QKVLD + h * 64];
  short8 qf[4];
#pragma unroll
  for (int ks = 0; ks < 4; ++ks)
    qf[ks] = *(const short8*)&Qrow[ks * 16 + hi * 8];

  float lrow = 0.f;
  f32x16 accO[2];
#pragma unroll
  for (int dt = 0; dt < 2; ++dt)
#pragma unroll
    for (int r = 0; r < 16; ++r) accO[dt][r] = 0.f;

  // preload tile jbeg
  uint4 kv0 = *(const uint4*)(Kbase + (size_t)jbeg * QKVLD);
  uint4 kv1 = *(const uint4*)(Kbase + (size_t)jbeg * QKVLD + Krow32);
  uint4 vv0 = *(const uint4*)(Vbase + jbeg);
  uint4 vv1 = *(const uint4*)(Vbase + jbeg + 32 * SEQL);

  for (int j0 = jbeg; j0 < jend; j0 += 64) {
    __syncthreads();   // prior compute's LDS reads done
    *(uint4*)&Ks[lr * 72 + lc8] = kv0;
    *(uint4*)&Ks[(lr + 32) * 72 + lc8] = kv1;
    *(uint4*)&Vs[lr * 72 + lc8] = vv0;
    *(uint4*)&Vs[(lr + 32) * 72 + lc8] = vv1;
    __syncthreads();

    // prefetch next tile (issued early; consumed after next barrier)
    if (j0 + 64 < jend) {
      const unsigned short* kp = Kbase + (size_t)(j0 + 64) * QKVLD;
      const unsigned short* vp = Vbase + (j0 + 64);
      kv0 = *(const uint4*)(kp);
      kv1 = *(const uint4*)(kp + Krow32);
      vv0 = *(const uint4*)(vp);
      vv1 = *(const uint4*)(vp + 32 * SEQL);
    }

#pragma unroll
    for (int jt = 0; jt < 2; ++jt) {
      // S^T tile: z[reg] = S[j = j0+jt*32+(reg&3)+8*(reg>>2)+4*hi][q=l32]
      f32x16 z;
#pragma unroll
      for (int r = 0; r < 16; ++r) z[r] = 0.f;
#pragma unroll
      for (int ks = 0; ks < 4; ++ks) {
        const short8 ka =
            *(const short8*)&Ks[(jt * 32 + l32) * 72 + ks * 16 + hi * 8];
        z = __builtin_amdgcn_mfma_f32_32x32x16_bf16(ka, qf[ks], z, 0, 0, 0);
      }

      // mask -> exp -> pack (P values bf16, still per-lane)
      int pk[8];
#pragma unroll
      for (int g = 0; g < 4; ++g) {
        const int4 mm =
            *(const int4*)&mask[b * SEQL + j0 + jt * 32 + g * 8 + hi * 4];
        const int mr[4] = {mm.x, mm.y, mm.z, mm.w};
        float p[4];
#pragma unroll
        for (int e = 0; e < 4; ++e) {
          const float x = mr[e] ? z[g * 4 + e] * (1.0f / 1024.0f) : NEGINF;
          p[e] = __expf(x);
          lrow += p[e];
        }
        pk[g * 2 + 0] = cvtpk(p[0], p[1]);
        pk[g * 2 + 1] = cvtpk(p[2], p[3]);
      }
      // rebuild PV A-frags: lane must hold P[q=l32][j-slice hi*8+e (+16ks2)]
      pswap(pk[0], pk[2]); pswap(pk[1], pk[3]);   // j 0..15 slice
      pswap(pk[4], pk[6]); pswap(pk[5], pk[7]);   // j 16..31 slice
      union { int i[4]; short8 s; } pa0, pa1;
      pa0.i[0] = pk[0]; pa0.i[1] = pk[1]; pa0.i[2] = pk[2]; pa0.i[3] = pk[3];
      pa1.i[0] = pk[4]; pa1.i[1] = pk[5]; pa1.i[2] = pk[6]; pa1.i[3] = pk[7];

      // O += P V : B-frag = V[j][d] from Vs[d][j]
#pragma unroll
      for (int dt = 0; dt < 2; ++dt) {
        const short8 vb0 = *(const short8*)&Vs[(dt * 32 + l32) * 72 +
                                               jt * 32 + hi * 8];
        const short8 vb1 = *(const short8*)&Vs[(dt * 32 + l32) * 72 +
                                               jt * 32 + 16 + hi * 8];
        accO[dt] = __builtin_amdgcn_mfma_f32_32x32x16_bf16(pa0.s, vb0,
                                                           accO[dt], 0, 0, 0);
        accO[dt] = __builtin_amdgcn_mfma_f32_32x32x16_bf16(pa1.s, vb1,
                                                           accO[dt], 0, 0, 0);
      }
    }
  }

  // row-sum: lanes l and l+32 hold disjoint j-partials of the same q=l32
  lrow += __shfl_xor(lrow, 32);
  if (hi == 0)
    ls[((size_t)(jh * NB + b) * NHEADS + h) * SEQL + q0 + wave * 32 + l32] =
        lrow;

  // Op write: C layout col=d=l32(+dt*32), row q = (reg&3)+8*(reg>>2)+4*hi
#pragma unroll
  for (int dt = 0; dt < 2; ++dt)
#pragma unroll
    for (int r = 0; r < 16; ++r) {
      const int qr = q0 + wave * 32 + (r & 3) + 8 * (r >> 2) + 4 * hi;
      const int rowg = b * SEQL + qr;
      Op[(size_t)jh * ROWS * Hd + (size_t)rowg * Hd + h * 64 + dt * 32 + l32] =
          f2bf_fast(accO[dt][r]);
    }
}

// ---------------------------------------------------------------------------
// ctx = (O0 + O1) / (l0 + l1). grid = ROWS, 256 thr x 4 cols.
// ---------------------------------------------------------------------------
__global__ __launch_bounds__(256) void attn_combine(
    const unsigned short* __restrict__ Op, const float* __restrict__ ls,
    unsigned short* __restrict__ ctxb) {
  const int row = blockIdx.x;
  const int b = row >> 11, q = row & (SEQL - 1);
  const int t = threadIdx.x;
  const int c0 = t * 4, h = t >> 4;
  const float l0 = ls[((size_t)(b)*NHEADS + h) * SEQL + q];
  const float l1 = ls[((size_t)(NB + b) * NHEADS + h) * SEQL + q];
  const float inv = 1.0f / (l0 + l1);
  ushort4 a = *(const ushort4*)&Op[(size_t)row * Hd + c0];
  ushort4 c = *(const ushort4*)&Op[(size_t)ROWS * Hd + (size_t)row * Hd + c0];
  ushort4 o;
  o.x = f2bf_fast((bf2f(a.x) + bf2f(c.x)) * inv);
  o.y = f2bf_fast((bf2f(a.y) + bf2f(c.y)) * inv);
  o.z = f2bf_fast((bf2f(a.z) + bf2f(c.z)) * inv);
  o.w = f2bf_fast((bf2f(a.w) + bf2f(c.w)) * inv);
  *(ushort4*)&ctxb[(size_t)row * Hd + c0] = o;
}

// ---------------------------------------------------------------------------
// out = LayerNorm(A + R)*g + b. ABF: A is bf16 (else fp32). In-place safe.
// ---------------------------------------------------------------------------
template <int ABF>
__global__ __launch_bounds__(256) void add_ln_kernel(
    const void* Av, const float* R,
    const float* __restrict__ gamma, const float* __restrict__ beta,
    float* out, unsigned short* outb) {
  const int row = blockIdx.x;
  const int t = threadIdx.x;
  const size_t baser = (size_t)row * Hd;

  float a0, a1, a2, a3;
  if (ABF) {
    ushort4 a = *(const ushort4*)&((const unsigned short*)Av)[baser + t * 4];
    a0 = bf2f(a.x); a1 = bf2f(a.y); a2 = bf2f(a.z); a3 = bf2f(a.w);
  } else {
    float4 a = *(const float4*)&((const float*)Av)[baser + t * 4];
    a0 = a.x; a1 = a.y; a2 = a.z; a3 = a.w;
  }
  float4 r = *(const float4*)&R[baser + t * 4];
  float x0 = a0 + r.x, x1 = a1 + r.y, x2 = a2 + r.z, x3 = a3 + r.w;
  float s  = x0 + x1 + x2 + x3;
  float ss = x0 * x0 + x1 * x1 + x2 * x2 + x3 * x3;

#pragma unroll
  for (int off = 32; off > 0; off >>= 1) {
    s  += __shfl_down(s, off, 64);
    ss += __shfl_down(ss, off, 64);
  }

  __shared__ float rs[4], rss[4];
  __shared__ float sh_mean, sh_rstd;
  if ((t & 63) == 0) { rs[t >> 6] = s; rss[t >> 6] = ss; }
  __syncthreads();
  if (t == 0) {
    const float S  = rs[0] + rs[1] + rs[2] + rs[3];
    const float SS = rss[0] + rss[1] + rss[2] + rss[3];
    const float mean = S * (1.0f / Hd);
    const float var  = SS * (1.0f / Hd) - mean * mean;
    sh_mean = mean;
    sh_rstd = rsqrtf(var + 1e-5f);
  }
  __syncthreads();
  const float mean = sh_mean, rstd = sh_rstd;

  float4 gm = *(const float4*)&gamma[t * 4];
  float4 bt = *(const float4*)&beta[t * 4];
  float4 o;
  o.x = (x0 - mean) * rstd * gm.x + bt.x;
  o.y = (x1 - mean) * rstd * gm.y + bt.y;
  o.z = (x2 - mean) * rstd * gm.z + bt.z;
  o.w = (x3 - mean) * rstd * gm.w + bt.w;
  *(float4*)&out[baser + t * 4] = o;
  if (outb) {
    ushort4 ob;
    ob.x = f2bf(o.x); ob.y = f2bf(o.y); ob.z = f2bf(o.z); ob.w = f2bf(o.w);
    *(ushort4*)&outb[baser + t * 4] = ob;
  }
}

// ---------------------------------------------------------------------------
// ws (48MB): P1: 0-8 srcb | 8-14 WqkvT | 14 bqkv | 16-40 qkv | 40-48 vt.
// attn: Opart 0-16 (srcb/WqkvT dead). d_out: ls +8, WoT +9-11, ctxb 0-8.
// Wo-gemm -> mhsa ws 16-32. LN1 -> x1 fp32 = d_out 0-16 (ctxb/ls/WoT dead),
// x1b ws 8-16. W1T full ws 0-8 -> FFN1 -> hb ws 16-48 (32MB). W2T full
// ws 0-8 -> FFN2 K=4096 -> f2b bf16 ws 8-16 (x1b dead). LN2(f2b, x1) ->
// d_out in-place.
// ---------------------------------------------------------------------------
extern "C" void kernel_launch(void* const* d_in, const int* in_sizes, int n_in,
                              void* d_out, int out_size, void* d_ws, size_t ws_size,
                              hipStream_t stream) {
  const float* src  = (const float*)d_in[0];
  const int*   kmsk = (const int*)  d_in[1];
  const float* Wq   = (const float*)d_in[2];
  const float* bq   = (const float*)d_in[3];
  const float* Wk   = (const float*)d_in[4];
  const float* bk   = (const float*)d_in[5];
  const float* Wv   = (const float*)d_in[6];
  const float* bv   = (const float*)d_in[7];
  const float* Wo   = (const float*)d_in[8];
  const float* bo   = (const float*)d_in[9];
  const float* ln1g = (const float*)d_in[10];
  const float* ln1b = (const float*)d_in[11];
  const float* W1   = (const float*)d_in[12];
  const float* b1   = (const float*)d_in[13];
  const float* W2   = (const float*)d_in[14];
  const float* b2   = (const float*)d_in[15];
  const float* ln2g = (const float*)d_in[16];
  const float* ln2b = (const float*)d_in[17];

  char* w8 = (char*)d_ws;
  char* o8 = (char*)d_out;
  const size_t MB = 1024 * 1024;
  unsigned short* srcb  = (unsigned short*)(w8 + 0 * MB);
  unsigned short* WqkvT = (unsigned short*)(w8 + 8 * MB);
  float*          bqkv  = (float*)(w8 + 14 * MB);
  unsigned short* qkv   = (unsigned short*)(w8 + 16 * MB);
  unsigned short* vt    = (unsigned short*)(w8 + 40 * MB);
  unsigned short* Opart = (unsigned short*)(w8 + 0 * MB);   // 16 MB
  float*          ls    = (float*)(o8 + 8 * MB);            // 512 KB
  unsigned short* WoT   = (unsigned short*)(o8 + 9 * MB);   // 2 MB
  unsigned short* ctxb  = (unsigned short*)d_out;           // 8 MB
  float*          mhsa  = (float*)(w8 + 16 * MB);           // 16 MB
  float*          x1    = (float*)d_out;                    // 16 MB fp32
  unsigned short* x1b   = (unsigned short*)(w8 + 8 * MB);   // 8 MB
  unsigned short* W1T   = (unsigned short*)(w8 + 0 * MB);   // 8 MB full
  unsigned short* hb    = (unsigned short*)(w8 + 16 * MB);  // 32 MB full
  unsigned short* W2T   = (unsigned short*)(w8 + 0 * MB);   // 8 MB full
  unsigned short* f2b   = (unsigned short*)(w8 + 8 * MB);   // 8 MB

  dim3 blk(256);

  convert_bf16<<<ROWS * Hd / 1024 + 12, blk, 0, stream>>>(
      src, srcb, bq, bk, bv, bqkv);
  convert_transpose4<<<dim3(16, 16, 4), blk, 0, stream>>>(
      Wq, Wk, Wv, Wo, WqkvT, WqkvT + 1024 * 1024, WqkvT + 2 * 1024 * 1024, WoT);

  // fused QKV: [4096][3072] = srcb @ WqkvT^T  (BK=64, grid 24x32)
  gemm_bt<128, 0, 1><<<dim3(QKVLD / 128, ROWS / 128), blk, 0, stream>>>(
      srcb, Hd, WqkvT, Hd, bqkv, qkv, QKVLD, Hd);

  transpose_v<<<1024, blk, 0, stream>>>(qkv + 2048, vt);
  attn_mfma<<<1024, blk, 0, stream>>>(qkv, qkv + 1024, vt, kmsk, Opart, ls);
  attn_combine<<<ROWS, blk, 0, stream>>>(Opart, ls, ctxb);

  gemm_bt<64, 0, 0><<<dim3(Hd / 64, ROWS / 128), blk, 0, stream>>>(
      ctxb, Hd, WoT, Hd, bo, mhsa, Hd, Hd);

  add_ln_kernel<0><<<ROWS, blk, 0, stream>>>(mhsa, src, ln1g, ln1b, x1, x1b);

  // FFN single-pass: W1T [4096][1024], hb [4096][4096] bf16, W2T [1024][4096]
  convert_transpose<<<dim3(64, 16), blk, 0, stream>>>(W1, FFND, W1T, Hd);
  gemm_bt<128, 1, 1><<<dim3(FFND / 128, ROWS / 128), blk, 0, stream>>>(
      x1b, Hd, W1T, Hd, b1, hb, FFND, Hd);
  convert_transpose<<<dim3(16, 64), blk, 0, stream>>>(W2, Hd, W2T, FFND);
  gemm_bt<64, 0, 1><<<dim3(Hd / 64, ROWS / 128), blk, 0, stream>>>(
      hb, FFND, W2T, FFND, b2, f2b, Hd, FFND);

  add_ln_kernel<1><<<ROWS, blk, 0, stream>>>(f2b, x1, ln2g, ln2b,
                                             (float*)d_out, nullptr);
}

// Round 8
// 356.600 us; speedup vs baseline: 1.0922x; 1.0617x over previous
//
#include <hip/hip_runtime.h>
#include <math.h>

#define Hd   1024
#define SEQL 2048
#define NB   2
#define NHEADS 16
#define FFND 4096
#define ROWS 4096
#define QKVLD 3072

typedef __attribute__((ext_vector_type(8))) short short8;    // 8 bf16
typedef __attribute__((ext_vector_type(4))) float f32x4;     // 16x16 acc
typedef __attribute__((ext_vector_type(16))) float f32x16;   // 32x32 acc

__device__ __forceinline__ unsigned short f2bf(float f) {   // RNE (converts)
  union { float f; unsigned int u; } v; v.f = f;
  return (unsigned short)((v.u + 0x7fffu + ((v.u >> 16) & 1u)) >> 16);
}
__device__ __forceinline__ unsigned short f2bf_fast(float f) {  // round-half-up
  union { float f; unsigned int u; } v; v.f = f;
  return (unsigned short)((v.u + 0x8000u) >> 16);
}
__device__ __forceinline__ float bf2f(unsigned short u) {
  union { unsigned int u; float f; } v; v.u = (unsigned int)u << 16;
  return v.f;
}
// pack two f32 -> 2 bf16 in one dword (lo = a, hi = b); no builtin (m240)
__device__ __forceinline__ int cvtpk(float a, float b) {
  int d;
  asm("v_cvt_pk_bf16_f32 %0, %1, %2" : "=v"(d) : "v"(a), "v"(b));
  return d;
}
// swap a's lanes 32-63 with b's lanes 0-31 (pure VALU, no mem ordering issues)
__device__ __forceinline__ void pswap(int& a, int& b) {
  asm("v_permlane32_swap_b32 %0, %1" : "+v"(a), "+v"(b));
}

// async global->LDS, 16 B/lane; lds dst is wave-uniform base (HW adds lane*16)
__device__ __forceinline__ void gl_lds16(const unsigned short* g,
                                         unsigned short* l) {
  __builtin_amdgcn_global_load_lds(
      (const __attribute__((address_space(1))) void*)g,
      (__attribute__((address_space(3))) void*)l, 16, 0, 0);
}

// ---------------------------------------------------------------------------
// fp32 -> bf16 bulk convert; extra blocks: bias concat (12) + mask->f32 bias
// (16: maskb[i] = kmsk[i] ? 0 : -inf, consumed by attn's exp2-fused softmax).
// grid = 4096 + 12 + 16.
// ---------------------------------------------------------------------------
__global__ __launch_bounds__(256) void convert_bf16(
    const float* __restrict__ in, unsigned short* __restrict__ out,
    const float* __restrict__ a, const float* __restrict__ b,
    const float* __restrict__ c, float* __restrict__ o,
    const int* __restrict__ kmsk, float* __restrict__ maskb) {
  const int bid = blockIdx.x;
  const int NCONV = ROWS * Hd / 1024;
  if (bid >= NCONV + 12) {
    const int i = (bid - NCONV - 12) * 256 + threadIdx.x;
    maskb[i] = kmsk[i] ? 0.0f : -__builtin_inff();
    return;
  }
  if (bid >= NCONV) {
    const int i = (bid - NCONV) * 256 + threadIdx.x;
    o[i] = (i < 1024) ? a[i] : (i < 2048 ? b[i - 1024] : c[i - 2048]);
    return;
  }
  const int i = (bid * 256 + threadIdx.x) * 4;
  float4 x = *(const float4*)&in[i];
  ushort4 ov;
  ov.x = f2bf(x.x); ov.y = f2bf(x.y); ov.z = f2bf(x.z); ov.w = f2bf(x.w);
  *(ushort4*)&out[i] = ov;
}

// W[rows][cols] fp32 (ld) -> Wt[cols][rows] bf16 (ldt). grid=(cols/64, rows/64)
__global__ __launch_bounds__(256) void convert_transpose(
    const float* __restrict__ W, int ld,
    unsigned short* __restrict__ Wt, int ldt) {
  __shared__ float T[64][65];
  const int t = threadIdx.x;
  const int c0 = blockIdx.x * 64, r0 = blockIdx.y * 64;
#pragma unroll
  for (int p = 0; p < 4; ++p) {
    const int lin = t + p * 256;
    const int r = lin >> 4, c4 = (lin & 15) * 4;
    float4 x = *(const float4*)&W[(size_t)(r0 + r) * ld + c0 + c4];
    T[r][c4 + 0] = x.x; T[r][c4 + 1] = x.y;
    T[r][c4 + 2] = x.z; T[r][c4 + 3] = x.w;
  }
  __syncthreads();
#pragma unroll
  for (int p = 0; p < 2; ++p) {
    const int lin = t + p * 256;
    const int oc = lin >> 3, ch = (lin & 7) * 8;
    union { unsigned short u[8]; uint4 v; } x;
#pragma unroll
    for (int i = 0; i < 8; ++i) x.u[i] = f2bf(T[ch + i][oc]);
    *(uint4*)&Wt[(size_t)(c0 + oc) * ldt + r0 + ch] = x.v;
  }
}

// 4x 1024x1024 fp32 -> transposed bf16 in one launch. grid=(16,16,4).
__global__ __launch_bounds__(256) void convert_transpose4(
    const float* __restrict__ W0, const float* __restrict__ W1,
    const float* __restrict__ W2, const float* __restrict__ W3,
    unsigned short* __restrict__ T0, unsigned short* __restrict__ T1,
    unsigned short* __restrict__ T2, unsigned short* __restrict__ T3) {
  __shared__ float T[64][65];
  const float* W = (blockIdx.z == 0) ? W0 : (blockIdx.z == 1) ? W1
                 : (blockIdx.z == 2) ? W2 : W3;
  unsigned short* Wt = (blockIdx.z == 0) ? T0 : (blockIdx.z == 1) ? T1
                     : (blockIdx.z == 2) ? T2 : T3;
  const int t = threadIdx.x;
  const int c0 = blockIdx.x * 64, r0 = blockIdx.y * 64;
#pragma unroll
  for (int p = 0; p < 4; ++p) {
    const int lin = t + p * 256;
    const int r = lin >> 4, c4 = (lin & 15) * 4;
    float4 x = *(const float4*)&W[(size_t)(r0 + r) * Hd + c0 + c4];
    T[r][c4 + 0] = x.x; T[r][c4 + 1] = x.y;
    T[r][c4 + 2] = x.z; T[r][c4 + 3] = x.w;
  }
  __syncthreads();
#pragma unroll
  for (int p = 0; p < 2; ++p) {
    const int lin = t + p * 256;
    const int oc = lin >> 3, ch = (lin & 7) * 8;
    union { unsigned short u[8]; uint4 v; } x;
#pragma unroll
    for (int i = 0; i < 8; ++i) x.u[i] = f2bf(T[ch + i][oc]);
    *(uint4*)&Wt[(size_t)(c0 + oc) * Hd + r0 + ch] = x.v;
  }
}

// v-region bf16 [ROWS][QKVLD] -> vt [(b*16+h)*64+d][SEQL]. grid = 32*32
__global__ __launch_bounds__(256) void transpose_v(
    const unsigned short* __restrict__ v, unsigned short* __restrict__ vt) {
  __shared__ unsigned short T[64][72];
  const int t = threadIdx.x;
  const int s0 = (blockIdx.x & 31) * 64;
  const int bh = blockIdx.x >> 5;
  const int b = bh >> 4, h = bh & 15;
#pragma unroll
  for (int p = 0; p < 2; ++p) {
    const int lin = t + p * 256;
    const int r = lin >> 3, c8 = (lin & 7) * 8;
    *(uint4*)&T[r][c8] =
        *(const uint4*)&v[(size_t)(b * SEQL + s0 + r) * QKVLD + h * 64 + c8];
  }
  __syncthreads();
#pragma unroll
  for (int p = 0; p < 2; ++p) {
    const int lin = t + p * 256;
    const int d = lin >> 3, c8 = (lin & 7) * 8;
    union { unsigned short u[8]; uint4 v4; } x;
#pragma unroll
    for (int i = 0; i < 8; ++i) x.u[i] = T[c8 + i][d];
    *(uint4*)&vt[(size_t)(bh * 64 + d) * SEQL + s0 + c8] = x.v4;
  }
}

// ---------------------------------------------------------------------------
// bf16 MFMA GEMM, R14 config (best measured) + R17 XCD-aware block swizzle
// (T1): consecutive linear block ids share the A panel; chunking them onto
// one XCD keeps the panel in that XCD's L2. All grids have nwg%8==0 so the
// simple form is bijective. MODE 0:=+bias 1:relu 2:+= .
// ---------------------------------------------------------------------------
template <int BN, int MODE, int OUTBF>
__global__ __launch_bounds__(256, (BN == 128 ? 3 : 4)) void gemm_bt(
    const unsigned short* __restrict__ A, int lda,
    const unsigned short* __restrict__ Bt, int ldb,
    const float* __restrict__ bias,
    void* __restrict__ Cv, int ldc, int K) {
  constexpr int NI = (BN == 128) ? 4 : 2;
  constexpr int BG = BN / 32;              // B wave-ops per K-step (2 or 4)
  __shared__ unsigned short As[128 * 64];
  __shared__ unsigned short Bs[BN * 64];
  const int t = threadIdx.x;
  const int wave = t >> 6, lane = t & 63;
  const int l16 = lane & 15, quad = lane >> 4;

  // XCD swizzle (nwg % 8 == 0 for all call sites -> bijective)
  const int gx = gridDim.x;
  const int nwg = gx * gridDim.y;
  const int id = blockIdx.y * gx + blockIdx.x;
  const int swz = (id & 7) * (nwg >> 3) + (id >> 3);
  const int m0 = (swz / gx) * 128, n0 = (swz % gx) * BN;

  const int wm = (wave >> 1) * 64, wn = (wave & 1) * (BN / 2);

  const int lr8 = lane >> 3;                    // 0..7 local row
  const int sc8 = 8 * ((lane & 7) ^ lr8);       // pre-swizzled source slot

  f32x4 acc[4][NI];
#pragma unroll
  for (int i = 0; i < 4; ++i)
#pragma unroll
    for (int j = 0; j < NI; ++j) acc[i][j] = (f32x4){0.f, 0.f, 0.f, 0.f};

  const unsigned short* Apg[4];
  unsigned short* lAg[4];
#pragma unroll
  for (int j = 0; j < 4; ++j) {
    const int r0 = (wave + 4 * j) * 8;
    Apg[j] = &A[(size_t)(m0 + r0 + lr8) * lda + sc8];
    lAg[j] = &As[r0 * 64];
  }
  const unsigned short* Bpg[BG];
  unsigned short* lBg[BG];
#pragma unroll
  for (int j = 0; j < BG; ++j) {
    const int r0 = (wave + 4 * j) * 8;
    Bpg[j] = &Bt[(size_t)(n0 + r0 + lr8) * ldb + sc8];
    lBg[j] = &Bs[r0 * 64];
  }

  for (int k0 = 0; k0 < K; k0 += 64) {
#pragma unroll
    for (int j = 0; j < 4; ++j) gl_lds16(Apg[j] + k0, lAg[j]);
#pragma unroll
    for (int j = 0; j < BG; ++j) gl_lds16(Bpg[j] + k0, lBg[j]);
    __syncthreads();   // drains vmcnt -> staging visible

#pragma unroll
    for (int kh = 0; kh < 2; ++kh) {
      short8 af[4], bfr[NI];
#pragma unroll
      for (int mi = 0; mi < 4; ++mi) {
        const int r = wm + mi * 16 + l16;
        af[mi] = *(const short8*)&As[r * 64 + (((quad + 4 * kh) ^ (r & 7)) * 8)];
      }
#pragma unroll
      for (int ni = 0; ni < NI; ++ni) {
        const int r = wn + ni * 16 + l16;
        bfr[ni] = *(const short8*)&Bs[r * 64 + (((quad + 4 * kh) ^ (r & 7)) * 8)];
      }
#pragma unroll
      for (int mi = 0; mi < 4; ++mi)
#pragma unroll
        for (int ni = 0; ni < NI; ++ni)
          acc[mi][ni] = __builtin_amdgcn_mfma_f32_16x16x32_bf16(
              af[mi], bfr[ni], acc[mi][ni], 0, 0, 0);
    }
    __syncthreads();   // all frag reads done before next DMA lands
  }

#pragma unroll
  for (int mi = 0; mi < 4; ++mi) {
#pragma unroll
    for (int ni = 0; ni < NI; ++ni) {
      const int col = n0 + wn + ni * 16 + l16;
      const float bv = (MODE == 2) ? 0.0f : bias[col];
#pragma unroll
      for (int r = 0; r < 4; ++r) {
        const int row = m0 + wm + mi * 16 + quad * 4 + r;
        float v = acc[mi][ni][r] + bv;
        if (MODE == 1) v = fmaxf(v, 0.0f);
        if (OUTBF) {
          ((unsigned short*)Cv)[(size_t)row * ldc + col] = f2bf_fast(v);
        } else {
          float* Cf = (float*)Cv;
          if (MODE == 2) Cf[(size_t)row * ldc + col] += v;
          else           Cf[(size_t)row * ldc + col] = v;
        }
      }
    }
  }
}

// ---------------------------------------------------------------------------
// R17: MFMA flash attention, 32x32 in-register softmax (R16, 0 bank
// conflicts) + exp2 fusion (VALUBusy was 48% = top pipe):
//  * per-element softmax 5 ops -> 2: p = v_exp(fma(z, log2e/1024, mb)),
//    mb preloaded f32 {0,-inf} from maskb (no int mask, no cndmask chain).
//  * T5 setprio(1) around QK and PV MFMA clusters (+4-7% measured on attn).
// ---------------------------------------------------------------------------
__global__ __launch_bounds__(256, 4) void attn_mfma(
    const unsigned short* __restrict__ Q,
    const unsigned short* __restrict__ K,
    const unsigned short* __restrict__ Vt,
    const float* __restrict__ maskb,    // [NB][SEQL] {0,-inf}
    unsigned short* __restrict__ Op,    // [2][ROWS][Hd] bf16 partials
    float* __restrict__ ls) {           // [2][NB][NHEADS][SEQL]
  __shared__ unsigned short Ks[64 * 72];   // [j][d]
  __shared__ unsigned short Vs[64 * 72];   // [d][j]

  const int t = threadIdx.x;
  const int wave = t >> 6, lane = t & 63;
  const int l32 = lane & 31, hi = lane >> 5;
  const int qb = blockIdx.x & 15;
  const int h  = (blockIdx.x >> 4) & 15;
  const int b  = (blockIdx.x >> 8) & 1;
  const int jh = blockIdx.x >> 9;
  const int q0 = qb * 128;
  const int bh = b * NHEADS + h;
  const int jbeg = jh * (SEQL / 2), jend = jbeg + SEQL / 2;
  const float C2 = 1.4426950408889634f * (1.0f / 1024.0f);  // log2e/1024

  const int lr = t >> 3, lc8 = (t & 7) * 8;   // staging coords
  const unsigned short* Kbase = &K[(size_t)(b * SEQL + lr) * QKVLD + h * 64 + lc8];
  const unsigned short* Vbase = &Vt[(size_t)(bh * 64 + lr) * SEQL + lc8];
  const size_t Krow32 = (size_t)32 * QKVLD;   // +32 rows

  // Q as B-frags, straight from global: B[k=d][col=q], lane: q=l32, d=ks*16+hi*8+e
  const unsigned short* Qrow =
      &Q[(size_t)(b * SEQL + q0 + wave * 32 + l32) * QKVLD + h * 64];
  short8 qf[4];
#pragma unroll
  for (int ks = 0; ks < 4; ++ks)
    qf[ks] = *(const short8*)&Qrow[ks * 16 + hi * 8];

  float lrow = 0.f;
  f32x16 accO[2];
#pragma unroll
  for (int dt = 0; dt < 2; ++dt)
#pragma unroll
    for (int r = 0; r < 16; ++r) accO[dt][r] = 0.f;

  // preload tile jbeg
  uint4 kv0 = *(const uint4*)(Kbase + (size_t)jbeg * QKVLD);
  uint4 kv1 = *(const uint4*)(Kbase + (size_t)jbeg * QKVLD + Krow32);
  uint4 vv0 = *(const uint4*)(Vbase + jbeg);
  uint4 vv1 = *(const uint4*)(Vbase + jbeg + 32 * SEQL);

  for (int j0 = jbeg; j0 < jend; j0 += 64) {
    __syncthreads();   // prior compute's LDS reads done
    *(uint4*)&Ks[lr * 72 + lc8] = kv0;
    *(uint4*)&Ks[(lr + 32) * 72 + lc8] = kv1;
    *(uint4*)&Vs[lr * 72 + lc8] = vv0;
    *(uint4*)&Vs[(lr + 32) * 72 + lc8] = vv1;
    __syncthreads();

    // prefetch next tile (issued early; consumed after next barrier)
    if (j0 + 64 < jend) {
      const unsigned short* kp = Kbase + (size_t)(j0 + 64) * QKVLD;
      const unsigned short* vp = Vbase + (j0 + 64);
      kv0 = *(const uint4*)(kp);
      kv1 = *(const uint4*)(kp + Krow32);
      vv0 = *(const uint4*)(vp);
      vv1 = *(const uint4*)(vp + 32 * SEQL);
    }

#pragma unroll
    for (int jt = 0; jt < 2; ++jt) {
      // S^T tile: z[reg] = S[j = j0+jt*32+(reg&3)+8*(reg>>2)+4*hi][q=l32]
      f32x16 z;
#pragma unroll
      for (int r = 0; r < 16; ++r) z[r] = 0.f;
      __builtin_amdgcn_s_setprio(1);
#pragma unroll
      for (int ks = 0; ks < 4; ++ks) {
        const short8 ka =
            *(const short8*)&Ks[(jt * 32 + l32) * 72 + ks * 16 + hi * 8];
        z = __builtin_amdgcn_mfma_f32_32x32x16_bf16(ka, qf[ks], z, 0, 0, 0);
      }
      __builtin_amdgcn_s_setprio(0);

      // exp2-fused softmax: p = 2^(z*log2e/1024 + mb), mb in {0,-inf}
      int pk[8];
#pragma unroll
      for (int g = 0; g < 4; ++g) {
        const float4 mb =
            *(const float4*)&maskb[b * SEQL + j0 + jt * 32 + g * 8 + hi * 4];
        const float mbe[4] = {mb.x, mb.y, mb.z, mb.w};
        float p[4];
#pragma unroll
        for (int e = 0; e < 4; ++e) {
          const float x = fmaf(z[g * 4 + e], C2, mbe[e]);
          asm("v_exp_f32 %0, %1" : "=v"(p[e]) : "v"(x));
          lrow += p[e];
        }
        pk[g * 2 + 0] = cvtpk(p[0], p[1]);
        pk[g * 2 + 1] = cvtpk(p[2], p[3]);
      }
      // rebuild PV A-frags: lane must hold P[q=l32][j-slice hi*8+e (+16ks2)]
      pswap(pk[0], pk[2]); pswap(pk[1], pk[3]);   // j 0..15 slice
      pswap(pk[4], pk[6]); pswap(pk[5], pk[7]);   // j 16..31 slice
      union { int i[4]; short8 s; } pa0, pa1;
      pa0.i[0] = pk[0]; pa0.i[1] = pk[1]; pa0.i[2] = pk[2]; pa0.i[3] = pk[3];
      pa1.i[0] = pk[4]; pa1.i[1] = pk[5]; pa1.i[2] = pk[6]; pa1.i[3] = pk[7];

      // O += P V : B-frag = V[j][d] from Vs[d][j]
      __builtin_amdgcn_s_setprio(1);
#pragma unroll
      for (int dt = 0; dt < 2; ++dt) {
        const short8 vb0 = *(const short8*)&Vs[(dt * 32 + l32) * 72 +
                                               jt * 32 + hi * 8];
        const short8 vb1 = *(const short8*)&Vs[(dt * 32 + l32) * 72 +
                                               jt * 32 + 16 + hi * 8];
        accO[dt] = __builtin_amdgcn_mfma_f32_32x32x16_bf16(pa0.s, vb0,
                                                           accO[dt], 0, 0, 0);
        accO[dt] = __builtin_amdgcn_mfma_f32_32x32x16_bf16(pa1.s, vb1,
                                                           accO[dt], 0, 0, 0);
      }
      __builtin_amdgcn_s_setprio(0);
    }
  }

  // row-sum: lanes l and l+32 hold disjoint j-partials of the same q=l32
  lrow += __shfl_xor(lrow, 32);
  if (hi == 0)
    ls[((size_t)(jh * NB + b) * NHEADS + h) * SEQL + q0 + wave * 32 + l32] =
        lrow;

  // Op write: C layout col=d=l32(+dt*32), row q = (reg&3)+8*(reg>>2)+4*hi
#pragma unroll
  for (int dt = 0; dt < 2; ++dt)
#pragma unroll
    for (int r = 0; r < 16; ++r) {
      const int qr = q0 + wave * 32 + (r & 3) + 8 * (r >> 2) + 4 * hi;
      const int rowg = b * SEQL + qr;
      Op[(size_t)jh * ROWS * Hd + (size_t)rowg * Hd + h * 64 + dt * 32 + l32] =
          f2bf_fast(accO[dt][r]);
    }
}

// ---------------------------------------------------------------------------
// ctx = (O0 + O1) / (l0 + l1). grid = ROWS, 256 thr x 4 cols.
// ---------------------------------------------------------------------------
__global__ __launch_bounds__(256) void attn_combine(
    const unsigned short* __restrict__ Op, const float* __restrict__ ls,
    unsigned short* __restrict__ ctxb) {
  const int row = blockIdx.x;
  const int b = row >> 11, q = row & (SEQL - 1);
  const int t = threadIdx.x;
  const int c0 = t * 4, h = t >> 4;
  const float l0 = ls[((size_t)(b)*NHEADS + h) * SEQL + q];
  const float l1 = ls[((size_t)(NB + b) * NHEADS + h) * SEQL + q];
  const float inv = 1.0f / (l0 + l1);
  ushort4 a = *(const ushort4*)&Op[(size_t)row * Hd + c0];
  ushort4 c = *(const ushort4*)&Op[(size_t)ROWS * Hd + (size_t)row * Hd + c0];
  ushort4 o;
  o.x = f2bf_fast((bf2f(a.x) + bf2f(c.x)) * inv);
  o.y = f2bf_fast((bf2f(a.y) + bf2f(c.y)) * inv);
  o.z = f2bf_fast((bf2f(a.z) + bf2f(c.z)) * inv);
  o.w = f2bf_fast((bf2f(a.w) + bf2f(c.w)) * inv);
  *(ushort4*)&ctxb[(size_t)row * Hd + c0] = o;
}

// ---------------------------------------------------------------------------
// out = LayerNorm(A + R)*g + b. ABF: A is bf16 (else fp32). In-place safe.
// ---------------------------------------------------------------------------
template <int ABF>
__global__ __launch_bounds__(256) void add_ln_kernel(
    const void* Av, const float* R,
    const float* __restrict__ gamma, const float* __restrict__ beta,
    float* out, unsigned short* outb) {
  const int row = blockIdx.x;
  const int t = threadIdx.x;
  const size_t baser = (size_t)row * Hd;

  float a0, a1, a2, a3;
  if (ABF) {
    ushort4 a = *(const ushort4*)&((const unsigned short*)Av)[baser + t * 4];
    a0 = bf2f(a.x); a1 = bf2f(a.y); a2 = bf2f(a.z); a3 = bf2f(a.w);
  } else {
    float4 a = *(const float4*)&((const float*)Av)[baser + t * 4];
    a0 = a.x; a1 = a.y; a2 = a.z; a3 = a.w;
  }
  float4 r = *(const float4*)&R[baser + t * 4];
  float x0 = a0 + r.x, x1 = a1 + r.y, x2 = a2 + r.z, x3 = a3 + r.w;
  float s  = x0 + x1 + x2 + x3;
  float ss = x0 * x0 + x1 * x1 + x2 * x2 + x3 * x3;

#pragma unroll
  for (int off = 32; off > 0; off >>= 1) {
    s  += __shfl_down(s, off, 64);
    ss += __shfl_down(ss, off, 64);
  }

  __shared__ float rs[4], rss[4];
  __shared__ float sh_mean, sh_rstd;
  if ((t & 63) == 0) { rs[t >> 6] = s; rss[t >> 6] = ss; }
  __syncthreads();
  if (t == 0) {
    const float S  = rs[0] + rs[1] + rs[2] + rs[3];
    const float SS = rss[0] + rss[1] + rss[2] + rss[3];
    const float mean = S * (1.0f / Hd);
    const float var  = SS * (1.0f / Hd) - mean * mean;
    sh_mean = mean;
    sh_rstd = rsqrtf(var + 1e-5f);
  }
  __syncthreads();
  const float mean = sh_mean, rstd = sh_rstd;

  float4 gm = *(const float4*)&gamma[t * 4];
  float4 bt = *(const float4*)&beta[t * 4];
  float4 o;
  o.x = (x0 - mean) * rstd * gm.x + bt.x;
  o.y = (x1 - mean) * rstd * gm.y + bt.y;
  o.z = (x2 - mean) * rstd * gm.z + bt.z;
  o.w = (x3 - mean) * rstd * gm.w + bt.w;
  *(float4*)&out[baser + t * 4] = o;
  if (outb) {
    ushort4 ob;
    ob.x = f2bf(o.x); ob.y = f2bf(o.y); ob.z = f2bf(o.z); ob.w = f2bf(o.w);
    *(ushort4*)&outb[baser + t * 4] = ob;
  }
}

// ---------------------------------------------------------------------------
// ws (48MB): P1: 0-8 srcb | 8-14 WqkvT | 14 bqkv | 16-40 qkv | 40-48 vt.
// attn: Opart 0-16 (srcb/WqkvT dead). d_out: ls +8, maskb +8.5, WoT +9-11,
// ctxb 0-8. Wo-gemm -> mhsa ws 16-32. LN1 -> x1 fp32 = d_out 0-16
// (ctxb/ls/maskb/WoT dead), x1b ws 8-16. W1T ws 0-8 -> FFN1 -> hb ws 16-48.
// W2T ws 0-8 -> FFN2 K=4096 -> f2b ws 8-16 (x1b dead). LN2 -> d_out.
// ---------------------------------------------------------------------------
extern "C" void kernel_launch(void* const* d_in, const int* in_sizes, int n_in,
                              void* d_out, int out_size, void* d_ws, size_t ws_size,
                              hipStream_t stream) {
  const float* src  = (const float*)d_in[0];
  const int*   kmsk = (const int*)  d_in[1];
  const float* Wq   = (const float*)d_in[2];
  const float* bq   = (const float*)d_in[3];
  const float* Wk   = (const float*)d_in[4];
  const float* bk   = (const float*)d_in[5];
  const float* Wv   = (const float*)d_in[6];
  const float* bv   = (const float*)d_in[7];
  const float* Wo   = (const float*)d_in[8];
  const float* bo   = (const float*)d_in[9];
  const float* ln1g = (const float*)d_in[10];
  const float* ln1b = (const float*)d_in[11];
  const float* W1   = (const float*)d_in[12];
  const float* b1   = (const float*)d_in[13];
  const float* W2   = (const float*)d_in[14];
  const float* b2   = (const float*)d_in[15];
  const float* ln2g = (const float*)d_in[16];
  const float* ln2b = (const float*)d_in[17];

  char* w8 = (char*)d_ws;
  char* o8 = (char*)d_out;
  const size_t MB = 1024 * 1024;
  unsigned short* srcb  = (unsigned short*)(w8 + 0 * MB);
  unsigned short* WqkvT = (unsigned short*)(w8 + 8 * MB);
  float*          bqkv  = (float*)(w8 + 14 * MB);
  unsigned short* qkv   = (unsigned short*)(w8 + 16 * MB);
  unsigned short* vt    = (unsigned short*)(w8 + 40 * MB);
  unsigned short* Opart = (unsigned short*)(w8 + 0 * MB);   // 16 MB
  float*          ls    = (float*)(o8 + 8 * MB);            // 512 KB
  float*          maskb = (float*)(o8 + 8 * MB + 512 * 1024);  // 16 KB
  unsigned short* WoT   = (unsigned short*)(o8 + 9 * MB);   // 2 MB
  unsigned short* ctxb  = (unsigned short*)d_out;           // 8 MB
  float*          mhsa  = (float*)(w8 + 16 * MB);           // 16 MB
  float*          x1    = (float*)d_out;                    // 16 MB fp32
  unsigned short* x1b   = (unsigned short*)(w8 + 8 * MB);   // 8 MB
  unsigned short* W1T   = (unsigned short*)(w8 + 0 * MB);   // 8 MB full
  unsigned short* hb    = (unsigned short*)(w8 + 16 * MB);  // 32 MB full
  unsigned short* W2T   = (unsigned short*)(w8 + 0 * MB);   // 8 MB full
  unsigned short* f2b   = (unsigned short*)(w8 + 8 * MB);   // 8 MB

  dim3 blk(256);

  convert_bf16<<<ROWS * Hd / 1024 + 12 + 16, blk, 0, stream>>>(
      src, srcb, bq, bk, bv, bqkv, kmsk, maskb);
  convert_transpose4<<<dim3(16, 16, 4), blk, 0, stream>>>(
      Wq, Wk, Wv, Wo, WqkvT, WqkvT + 1024 * 1024, WqkvT + 2 * 1024 * 1024, WoT);

  // fused QKV: [4096][3072] = srcb @ WqkvT^T  (BK=64, grid 24x32)
  gemm_bt<128, 0, 1><<<dim3(QKVLD / 128, ROWS / 128), blk, 0, stream>>>(
      srcb, Hd, WqkvT, Hd, bqkv, qkv, QKVLD, Hd);

  transpose_v<<<1024, blk, 0, stream>>>(qkv + 2048, vt);
  attn_mfma<<<1024, blk, 0, stream>>>(qkv, qkv + 1024, vt, maskb, Opart, ls);
  attn_combine<<<ROWS, blk, 0, stream>>>(Opart, ls, ctxb);

  gemm_bt<64, 0, 0><<<dim3(Hd / 64, ROWS / 128), blk, 0, stream>>>(
      ctxb, Hd, WoT, Hd, bo, mhsa, Hd, Hd);

  add_ln_kernel<0><<<ROWS, blk, 0, stream>>>(mhsa, src, ln1g, ln1b, x1, x1b);

  // FFN single-pass: W1T [4096][1024], hb [4096][4096] bf16, W2T [1024][4096]
  convert_transpose<<<dim3(64, 16), blk, 0, stream>>>(W1, FFND, W1T, Hd);
  gemm_bt<128, 1, 1><<<dim3(FFND / 128, ROWS / 128), blk, 0, stream>>>(
      x1b, Hd, W1T, Hd, b1, hb, FFND, Hd);
  convert_transpose<<<dim3(16, 64), blk, 0, stream>>>(W2, Hd, W2T, FFND);
  gemm_bt<64, 0, 1><<<dim3(Hd / 64, ROWS / 128), blk, 0, stream>>>(
      hb, FFND, W2T, FFND, b2, f2b, Hd, FFND);

  add_ln_kernel<1><<<ROWS, blk, 0, stream>>>(f2b, x1, ln2g, ln2b,
                                             (float*)d_out, nullptr);
}

// Round 9
// 356.063 us; speedup vs baseline: 1.0938x; 1.0015x over previous
//
#include <hip/hip_runtime.h>
#include <math.h>

#define Hd   1024
#define SEQL 2048
#define NB   2
#define NHEADS 16
#define FFND 4096
#define ROWS 4096
#define QKVLD 3072

typedef __attribute__((ext_vector_type(8))) short short8;    // 8 bf16
typedef __attribute__((ext_vector_type(4))) float f32x4;     // 16x16 acc
typedef __attribute__((ext_vector_type(16))) float f32x16;   // 32x32 acc

__device__ __forceinline__ unsigned short f2bf(float f) {   // RNE (converts)
  union { float f; unsigned int u; } v; v.f = f;
  return (unsigned short)((v.u + 0x7fffu + ((v.u >> 16) & 1u)) >> 16);
}
__device__ __forceinline__ unsigned short f2bf_fast(float f) {  // round-half-up
  union { float f; unsigned int u; } v; v.f = f;
  return (unsigned short)((v.u + 0x8000u) >> 16);
}
__device__ __forceinline__ float bf2f(unsigned short u) {
  union { unsigned int u; float f; } v; v.u = (unsigned int)u << 16;
  return v.f;
}
// pack two f32 -> 2 bf16 in one dword (lo = a, hi = b); no builtin (m240)
__device__ __forceinline__ int cvtpk(float a, float b) {
  int d;
  asm("v_cvt_pk_bf16_f32 %0, %1, %2" : "=v"(d) : "v"(a), "v"(b));
  return d;
}
// swap a's lanes 32-63 with b's lanes 0-31 (pure VALU, no mem ordering issues)
__device__ __forceinline__ void pswap(int& a, int& b) {
  asm("v_permlane32_swap_b32 %0, %1" : "+v"(a), "+v"(b));
}

// async global->LDS, 16 B/lane; lds dst is wave-uniform base (HW adds lane*16)
__device__ __forceinline__ void gl_lds16(const unsigned short* g,
                                         unsigned short* l) {
  __builtin_amdgcn_global_load_lds(
      (const __attribute__((address_space(1))) void*)g,
      (__attribute__((address_space(3))) void*)l, 16, 0, 0);
}

// ---------------------------------------------------------------------------
// fp32 -> bf16 bulk convert; extra blocks: bias concat (12) + mask->f32 bias
// (16: maskb[i] = kmsk[i] ? 0 : -inf, consumed by attn's exp2-fused softmax).
// grid = 4096 + 12 + 16.
// ---------------------------------------------------------------------------
__global__ __launch_bounds__(256) void convert_bf16(
    const float* __restrict__ in, unsigned short* __restrict__ out,
    const float* __restrict__ a, const float* __restrict__ b,
    const float* __restrict__ c, float* __restrict__ o,
    const int* __restrict__ kmsk, float* __restrict__ maskb) {
  const int bid = blockIdx.x;
  const int NCONV = ROWS * Hd / 1024;
  if (bid >= NCONV + 12) {
    const int i = (bid - NCONV - 12) * 256 + threadIdx.x;
    maskb[i] = kmsk[i] ? 0.0f : -__builtin_inff();
    return;
  }
  if (bid >= NCONV) {
    const int i = (bid - NCONV) * 256 + threadIdx.x;
    o[i] = (i < 1024) ? a[i] : (i < 2048 ? b[i - 1024] : c[i - 2048]);
    return;
  }
  const int i = (bid * 256 + threadIdx.x) * 4;
  float4 x = *(const float4*)&in[i];
  ushort4 ov;
  ov.x = f2bf(x.x); ov.y = f2bf(x.y); ov.z = f2bf(x.z); ov.w = f2bf(x.w);
  *(ushort4*)&out[i] = ov;
}

// W[rows][cols] fp32 (ld) -> Wt[cols][rows] bf16 (ldt). grid=(cols/64, rows/64)
__global__ __launch_bounds__(256) void convert_transpose(
    const float* __restrict__ W, int ld,
    unsigned short* __restrict__ Wt, int ldt) {
  __shared__ float T[64][65];
  const int t = threadIdx.x;
  const int c0 = blockIdx.x * 64, r0 = blockIdx.y * 64;
#pragma unroll
  for (int p = 0; p < 4; ++p) {
    const int lin = t + p * 256;
    const int r = lin >> 4, c4 = (lin & 15) * 4;
    float4 x = *(const float4*)&W[(size_t)(r0 + r) * ld + c0 + c4];
    T[r][c4 + 0] = x.x; T[r][c4 + 1] = x.y;
    T[r][c4 + 2] = x.z; T[r][c4 + 3] = x.w;
  }
  __syncthreads();
#pragma unroll
  for (int p = 0; p < 2; ++p) {
    const int lin = t + p * 256;
    const int oc = lin >> 3, ch = (lin & 7) * 8;
    union { unsigned short u[8]; uint4 v; } x;
#pragma unroll
    for (int i = 0; i < 8; ++i) x.u[i] = f2bf(T[ch + i][oc]);
    *(uint4*)&Wt[(size_t)(c0 + oc) * ldt + r0 + ch] = x.v;
  }
}

// 4x 1024x1024 fp32 -> transposed bf16 in one launch. grid=(16,16,4).
__global__ __launch_bounds__(256) void convert_transpose4(
    const float* __restrict__ W0, const float* __restrict__ W1,
    const float* __restrict__ W2, const float* __restrict__ W3,
    unsigned short* __restrict__ T0, unsigned short* __restrict__ T1,
    unsigned short* __restrict__ T2, unsigned short* __restrict__ T3) {
  __shared__ float T[64][65];
  const float* W = (blockIdx.z == 0) ? W0 : (blockIdx.z == 1) ? W1
                 : (blockIdx.z == 2) ? W2 : W3;
  unsigned short* Wt = (blockIdx.z == 0) ? T0 : (blockIdx.z == 1) ? T1
                     : (blockIdx.z == 2) ? T2 : T3;
  const int t = threadIdx.x;
  const int c0 = blockIdx.x * 64, r0 = blockIdx.y * 64;
#pragma unroll
  for (int p = 0; p < 4; ++p) {
    const int lin = t + p * 256;
    const int r = lin >> 4, c4 = (lin & 15) * 4;
    float4 x = *(const float4*)&W[(size_t)(r0 + r) * Hd + c0 + c4];
    T[r][c4 + 0] = x.x; T[r][c4 + 1] = x.y;
    T[r][c4 + 2] = x.z; T[r][c4 + 3] = x.w;
  }
  __syncthreads();
#pragma unroll
  for (int p = 0; p < 2; ++p) {
    const int lin = t + p * 256;
    const int oc = lin >> 3, ch = (lin & 7) * 8;
    union { unsigned short u[8]; uint4 v; } x;
#pragma unroll
    for (int i = 0; i < 8; ++i) x.u[i] = f2bf(T[ch + i][oc]);
    *(uint4*)&Wt[(size_t)(c0 + oc) * Hd + r0 + ch] = x.v;
  }
}

// v-region bf16 [ROWS][QKVLD] -> vt [(b*16+h)*64+d][SEQL]. grid = 32*32
__global__ __launch_bounds__(256) void transpose_v(
    const unsigned short* __restrict__ v, unsigned short* __restrict__ vt) {
  __shared__ unsigned short T[64][72];
  const int t = threadIdx.x;
  const int s0 = (blockIdx.x & 31) * 64;
  const int bh = blockIdx.x >> 5;
  const int b = bh >> 4, h = bh & 15;
#pragma unroll
  for (int p = 0; p < 2; ++p) {
    const int lin = t + p * 256;
    const int r = lin >> 3, c8 = (lin & 7) * 8;
    *(uint4*)&T[r][c8] =
        *(const uint4*)&v[(size_t)(b * SEQL + s0 + r) * QKVLD + h * 64 + c8];
  }
  __syncthreads();
#pragma unroll
  for (int p = 0; p < 2; ++p) {
    const int lin = t + p * 256;
    const int d = lin >> 3, c8 = (lin & 7) * 8;
    union { unsigned short u[8]; uint4 v4; } x;
#pragma unroll
    for (int i = 0; i < 8; ++i) x.u[i] = T[c8 + i][d];
    *(uint4*)&vt[(size_t)(bh * 64 + d) * SEQL + s0 + c8] = x.v4;
  }
}

// ---------------------------------------------------------------------------
// bf16 MFMA GEMM. R18: DBUF template path.
//  * DBUF=0 (BN=128 / QKV+FFN1, 3-4 blocks/CU): R14 single-buffer — cross-
//    block wave overlap hides DMA latency (R15 evidence: dbuf neutral here).
//  * DBUF=1 (BN=64 / Wo+FFN2, GRID-limited to 2 blocks/CU): double-buffer,
//    one barrier per K-step; the barrier drains loads issued one full
//    compute phase earlier, so the ~200-400cyc L2 latency hides inside the
//    block instead of relying on co-resident blocks that don't exist.
//    LDS 48KB (<=3/CU cap, grid is the binding limit anyway).
// XOR swizzle (conflict-free b128) + XCD-aware block swizzle (T1) kept.
// MODE 0:=+bias 1:relu 2:+= ; OUTBF: bf16 out.
// ---------------------------------------------------------------------------
template <int BN, int MODE, int OUTBF, int DBUF>
__global__ __launch_bounds__(256, (BN == 128 ? 3 : (DBUF ? 3 : 4))) void gemm_bt(
    const unsigned short* __restrict__ A, int lda,
    const unsigned short* __restrict__ Bt, int ldb,
    const float* __restrict__ bias,
    void* __restrict__ Cv, int ldc, int K) {
  constexpr int NI = (BN == 128) ? 4 : 2;
  constexpr int BG = BN / 32;              // B wave-ops per K-step (2 or 4)
  constexpr int NBUF = DBUF ? 2 : 1;
  __shared__ unsigned short As[NBUF][128 * 64];
  __shared__ unsigned short Bs[NBUF][BN * 64];
  const int t = threadIdx.x;
  const int wave = t >> 6, lane = t & 63;
  const int l16 = lane & 15, quad = lane >> 4;

  // XCD swizzle (nwg % 8 == 0 for all call sites -> bijective)
  const int gx = gridDim.x;
  const int nwg = gx * gridDim.y;
  const int id = blockIdx.y * gx + blockIdx.x;
  const int swz = (id & 7) * (nwg >> 3) + (id >> 3);
  const int m0 = (swz / gx) * 128, n0 = (swz % gx) * BN;

  const int wm = (wave >> 1) * 64, wn = (wave & 1) * (BN / 2);

  const int lr8 = lane >> 3;                    // 0..7 local row
  const int sc8 = 8 * ((lane & 7) ^ lr8);       // pre-swizzled source slot

  f32x4 acc[4][NI];
#pragma unroll
  for (int i = 0; i < 4; ++i)
#pragma unroll
    for (int j = 0; j < NI; ++j) acc[i][j] = (f32x4){0.f, 0.f, 0.f, 0.f};

  const unsigned short* Apg[4];
  int lAo[4];
#pragma unroll
  for (int j = 0; j < 4; ++j) {
    const int r0 = (wave + 4 * j) * 8;
    Apg[j] = &A[(size_t)(m0 + r0 + lr8) * lda + sc8];
    lAo[j] = r0 * 64;
  }
  const unsigned short* Bpg[BG];
  int lBo[BG];
#pragma unroll
  for (int j = 0; j < BG; ++j) {
    const int r0 = (wave + 4 * j) * 8;
    Bpg[j] = &Bt[(size_t)(n0 + r0 + lr8) * ldb + sc8];
    lBo[j] = r0 * 64;
  }

  auto compute = [&](int buf) {
#pragma unroll
    for (int kh = 0; kh < 2; ++kh) {
      short8 af[4], bfr[NI];
#pragma unroll
      for (int mi = 0; mi < 4; ++mi) {
        const int r = wm + mi * 16 + l16;
        af[mi] =
            *(const short8*)&As[buf][r * 64 + (((quad + 4 * kh) ^ (r & 7)) * 8)];
      }
#pragma unroll
      for (int ni = 0; ni < NI; ++ni) {
        const int r = wn + ni * 16 + l16;
        bfr[ni] =
            *(const short8*)&Bs[buf][r * 64 + (((quad + 4 * kh) ^ (r & 7)) * 8)];
      }
#pragma unroll
      for (int mi = 0; mi < 4; ++mi)
#pragma unroll
        for (int ni = 0; ni < NI; ++ni)
          acc[mi][ni] = __builtin_amdgcn_mfma_f32_16x16x32_bf16(
              af[mi], bfr[ni], acc[mi][ni], 0, 0, 0);
    }
  };

  if constexpr (DBUF) {
    const int NT = K >> 6;
    // prologue: tile 0 -> buf 0
#pragma unroll
    for (int j = 0; j < 4; ++j) gl_lds16(Apg[j], &As[0][lAo[j]]);
#pragma unroll
    for (int j = 0; j < BG; ++j) gl_lds16(Bpg[j], &Bs[0][lBo[j]]);
    for (int tk = 0; tk < NT; ++tk) {
      const int cb = tk & 1, nb = cb ^ 1;
      __syncthreads();   // drains loads(tk), issued one compute-phase ago
      if (tk + 1 < NT) {
        const int k1 = (tk + 1) << 6;
#pragma unroll
        for (int j = 0; j < 4; ++j) gl_lds16(Apg[j] + k1, &As[nb][lAo[j]]);
#pragma unroll
        for (int j = 0; j < BG; ++j) gl_lds16(Bpg[j] + k1, &Bs[nb][lBo[j]]);
      }
      compute(cb);
      // no trailing barrier: next iteration's barrier orders compute(tk)
      // before loads(tk+2) overwrite buf cb.
    }
  } else {
    for (int k0 = 0; k0 < K; k0 += 64) {
#pragma unroll
      for (int j = 0; j < 4; ++j) gl_lds16(Apg[j] + k0, &As[0][lAo[j]]);
#pragma unroll
      for (int j = 0; j < BG; ++j) gl_lds16(Bpg[j] + k0, &Bs[0][lBo[j]]);
      __syncthreads();   // drains vmcnt -> staging visible
      compute(0);
      __syncthreads();   // all frag reads done before next DMA lands
    }
  }

#pragma unroll
  for (int mi = 0; mi < 4; ++mi) {
#pragma unroll
    for (int ni = 0; ni < NI; ++ni) {
      const int col = n0 + wn + ni * 16 + l16;
      const float bv = (MODE == 2) ? 0.0f : bias[col];
#pragma unroll
      for (int r = 0; r < 4; ++r) {
        const int row = m0 + wm + mi * 16 + quad * 4 + r;
        float v = acc[mi][ni][r] + bv;
        if (MODE == 1) v = fmaxf(v, 0.0f);
        if (OUTBF) {
          ((unsigned short*)Cv)[(size_t)row * ldc + col] = f2bf_fast(v);
        } else {
          float* Cf = (float*)Cv;
          if (MODE == 2) Cf[(size_t)row * ldc + col] += v;
          else           Cf[(size_t)row * ldc + col] = v;
        }
      }
    }
  }
}

// ---------------------------------------------------------------------------
// R17: MFMA flash attention, 32x32 in-register softmax (0 bank conflicts) +
// exp2-fused softmax + setprio. Unchanged (66.4 -> <60us measured).
// ---------------------------------------------------------------------------
__global__ __launch_bounds__(256, 4) void attn_mfma(
    const unsigned short* __restrict__ Q,
    const unsigned short* __restrict__ K,
    const unsigned short* __restrict__ Vt,
    const float* __restrict__ maskb,    // [NB][SEQL] {0,-inf}
    unsigned short* __restrict__ Op,    // [2][ROWS][Hd] bf16 partials
    float* __restrict__ ls) {           // [2][NB][NHEADS][SEQL]
  __shared__ unsigned short Ks[64 * 72];   // [j][d]
  __shared__ unsigned short Vs[64 * 72];   // [d][j]

  const int t = threadIdx.x;
  const int wave = t >> 6, lane = t & 63;
  const int l32 = lane & 31, hi = lane >> 5;
  const int qb = blockIdx.x & 15;
  const int h  = (blockIdx.x >> 4) & 15;
  const int b  = (blockIdx.x >> 8) & 1;
  const int jh = blockIdx.x >> 9;
  const int q0 = qb * 128;
  const int bh = b * NHEADS + h;
  const int jbeg = jh * (SEQL / 2), jend = jbeg + SEQL / 2;
  const float C2 = 1.4426950408889634f * (1.0f / 1024.0f);  // log2e/1024

  const int lr = t >> 3, lc8 = (t & 7) * 8;   // staging coords
  const unsigned short* Kbase = &K[(size_t)(b * SEQL + lr) * QKVLD + h * 64 + lc8];
  const unsigned short* Vbase = &Vt[(size_t)(bh * 64 + lr) * SEQL + lc8];
  const size_t Krow32 = (size_t)32 * QKVLD;   // +32 rows

  // Q as B-frags, straight from global: B[k=d][col=q], lane: q=l32, d=ks*16+hi*8+e
  const unsigned short* Qrow =
      &Q[(size_t)(b * SEQL + q0 + wave * 32 + l32) * QKVLD + h * 64];
  short8 qf[4];
#pragma unroll
  for (int ks = 0; ks < 4; ++ks)
    qf[ks] = *(const short8*)&Qrow[ks * 16 + hi * 8];

  float lrow = 0.f;
  f32x16 accO[2];
#pragma unroll
  for (int dt = 0; dt < 2; ++dt)
#pragma unroll
    for (int r = 0; r < 16; ++r) accO[dt][r] = 0.f;

  // preload tile jbeg
  uint4 kv0 = *(const uint4*)(Kbase + (size_t)jbeg * QKVLD);
  uint4 kv1 = *(const uint4*)(Kbase + (size_t)jbeg * QKVLD + Krow32);
  uint4 vv0 = *(const uint4*)(Vbase + jbeg);
  uint4 vv1 = *(const uint4*)(Vbase + jbeg + 32 * SEQL);

  for (int j0 = jbeg; j0 < jend; j0 += 64) {
    __syncthreads();   // prior compute's LDS reads done
    *(uint4*)&Ks[lr * 72 + lc8] = kv0;
    *(uint4*)&Ks[(lr + 32) * 72 + lc8] = kv1;
    *(uint4*)&Vs[lr * 72 + lc8] = vv0;
    *(uint4*)&Vs[(lr + 32) * 72 + lc8] = vv1;
    __syncthreads();

    // prefetch next tile (issued early; consumed after next barrier)
    if (j0 + 64 < jend) {
      const unsigned short* kp = Kbase + (size_t)(j0 + 64) * QKVLD;
      const unsigned short* vp = Vbase + (j0 + 64);
      kv0 = *(const uint4*)(kp);
      kv1 = *(const uint4*)(kp + Krow32);
      vv0 = *(const uint4*)(vp);
      vv1 = *(const uint4*)(vp + 32 * SEQL);
    }

#pragma unroll
    for (int jt = 0; jt < 2; ++jt) {
      // S^T tile: z[reg] = S[j = j0+jt*32+(reg&3)+8*(reg>>2)+4*hi][q=l32]
      f32x16 z;
#pragma unroll
      for (int r = 0; r < 16; ++r) z[r] = 0.f;
      __builtin_amdgcn_s_setprio(1);
#pragma unroll
      for (int ks = 0; ks < 4; ++ks) {
        const short8 ka =
            *(const short8*)&Ks[(jt * 32 + l32) * 72 + ks * 16 + hi * 8];
        z = __builtin_amdgcn_mfma_f32_32x32x16_bf16(ka, qf[ks], z, 0, 0, 0);
      }
      __builtin_amdgcn_s_setprio(0);

      // exp2-fused softmax: p = 2^(z*log2e/1024 + mb), mb in {0,-inf}
      int pk[8];
#pragma unroll
      for (int g = 0; g < 4; ++g) {
        const float4 mb =
            *(const float4*)&maskb[b * SEQL + j0 + jt * 32 + g * 8 + hi * 4];
        const float mbe[4] = {mb.x, mb.y, mb.z, mb.w};
        float p[4];
#pragma unroll
        for (int e = 0; e < 4; ++e) {
          const float x = fmaf(z[g * 4 + e], C2, mbe[e]);
          asm("v_exp_f32 %0, %1" : "=v"(p[e]) : "v"(x));
          lrow += p[e];
        }
        pk[g * 2 + 0] = cvtpk(p[0], p[1]);
        pk[g * 2 + 1] = cvtpk(p[2], p[3]);
      }
      // rebuild PV A-frags: lane must hold P[q=l32][j-slice hi*8+e (+16ks2)]
      pswap(pk[0], pk[2]); pswap(pk[1], pk[3]);   // j 0..15 slice
      pswap(pk[4], pk[6]); pswap(pk[5], pk[7]);   // j 16..31 slice
      union { int i[4]; short8 s; } pa0, pa1;
      pa0.i[0] = pk[0]; pa0.i[1] = pk[1]; pa0.i[2] = pk[2]; pa0.i[3] = pk[3];
      pa1.i[0] = pk[4]; pa1.i[1] = pk[5]; pa1.i[2] = pk[6]; pa1.i[3] = pk[7];

      // O += P V : B-frag = V[j][d] from Vs[d][j]
      __builtin_amdgcn_s_setprio(1);
#pragma unroll
      for (int dt = 0; dt < 2; ++dt) {
        const short8 vb0 = *(const short8*)&Vs[(dt * 32 + l32) * 72 +
                                               jt * 32 + hi * 8];
        const short8 vb1 = *(const short8*)&Vs[(dt * 32 + l32) * 72 +
                                               jt * 32 + 16 + hi * 8];
        accO[dt] = __builtin_amdgcn_mfma_f32_32x32x16_bf16(pa0.s, vb0,
                                                           accO[dt], 0, 0, 0);
        accO[dt] = __builtin_amdgcn_mfma_f32_32x32x16_bf16(pa1.s, vb1,
                                                           accO[dt], 0, 0, 0);
      }
      __builtin_amdgcn_s_setprio(0);
    }
  }

  // row-sum: lanes l and l+32 hold disjoint j-partials of the same q=l32
  lrow += __shfl_xor(lrow, 32);
  if (hi == 0)
    ls[((size_t)(jh * NB + b) * NHEADS + h) * SEQL + q0 + wave * 32 + l32] =
        lrow;

  // Op write: C layout col=d=l32(+dt*32), row q = (reg&3)+8*(reg>>2)+4*hi
#pragma unroll
  for (int dt = 0; dt < 2; ++dt)
#pragma unroll
    for (int r = 0; r < 16; ++r) {
      const int qr = q0 + wave * 32 + (r & 3) + 8 * (r >> 2) + 4 * hi;
      const int rowg = b * SEQL + qr;
      Op[(size_t)jh * ROWS * Hd + (size_t)rowg * Hd + h * 64 + dt * 32 + l32] =
          f2bf_fast(accO[dt][r]);
    }
}

// ---------------------------------------------------------------------------
// ctx = (O0 + O1) / (l0 + l1). grid = ROWS, 256 thr x 4 cols.
// ---------------------------------------------------------------------------
__global__ __launch_bounds__(256) void attn_combine(
    const unsigned short* __restrict__ Op, const float* __restrict__ ls,
    unsigned short* __restrict__ ctxb) {
  const int row = blockIdx.x;
  const int b = row >> 11, q = row & (SEQL - 1);
  const int t = threadIdx.x;
  const int c0 = t * 4, h = t >> 4;
  const float l0 = ls[((size_t)(b)*NHEADS + h) * SEQL + q];
  const float l1 = ls[((size_t)(NB + b) * NHEADS + h) * SEQL + q];
  const float inv = 1.0f / (l0 + l1);
  ushort4 a = *(const ushort4*)&Op[(size_t)row * Hd + c0];
  ushort4 c = *(const ushort4*)&Op[(size_t)ROWS * Hd + (size_t)row * Hd + c0];
  ushort4 o;
  o.x = f2bf_fast((bf2f(a.x) + bf2f(c.x)) * inv);
  o.y = f2bf_fast((bf2f(a.y) + bf2f(c.y)) * inv);
  o.z = f2bf_fast((bf2f(a.z) + bf2f(c.z)) * inv);
  o.w = f2bf_fast((bf2f(a.w) + bf2f(c.w)) * inv);
  *(ushort4*)&ctxb[(size_t)row * Hd + c0] = o;
}

// ---------------------------------------------------------------------------
// out = LayerNorm(A + R)*g + b. ABF: A is bf16 (else fp32). In-place safe.
// ---------------------------------------------------------------------------
template <int ABF>
__global__ __launch_bounds__(256) void add_ln_kernel(
    const void* Av, const float* R,
    const float* __restrict__ gamma, const float* __restrict__ beta,
    float* out, unsigned short* outb) {
  const int row = blockIdx.x;
  const int t = threadIdx.x;
  const size_t baser = (size_t)row * Hd;

  float a0, a1, a2, a3;
  if (ABF) {
    ushort4 a = *(const ushort4*)&((const unsigned short*)Av)[baser + t * 4];
    a0 = bf2f(a.x); a1 = bf2f(a.y); a2 = bf2f(a.z); a3 = bf2f(a.w);
  } else {
    float4 a = *(const float4*)&((const float*)Av)[baser + t * 4];
    a0 = a.x; a1 = a.y; a2 = a.z; a3 = a.w;
  }
  float4 r = *(const float4*)&R[baser + t * 4];
  float x0 = a0 + r.x, x1 = a1 + r.y, x2 = a2 + r.z, x3 = a3 + r.w;
  float s  = x0 + x1 + x2 + x3;
  float ss = x0 * x0 + x1 * x1 + x2 * x2 + x3 * x3;

#pragma unroll
  for (int off = 32; off > 0; off >>= 1) {
    s  += __shfl_down(s, off, 64);
    ss += __shfl_down(ss, off, 64);
  }

  __shared__ float rs[4], rss[4];
  __shared__ float sh_mean, sh_rstd;
  if ((t & 63) == 0) { rs[t >> 6] = s; rss[t >> 6] = ss; }
  __syncthreads();
  if (t == 0) {
    const float S  = rs[0] + rs[1] + rs[2] + rs[3];
    const float SS = rss[0] + rss[1] + rss[2] + rss[3];
    const float mean = S * (1.0f / Hd);
    const float var  = SS * (1.0f / Hd) - mean * mean;
    sh_mean = mean;
    sh_rstd = rsqrtf(var + 1e-5f);
  }
  __syncthreads();
  const float mean = sh_mean, rstd = sh_rstd;

  float4 gm = *(const float4*)&gamma[t * 4];
  float4 bt = *(const float4*)&beta[t * 4];
  float4 o;
  o.x = (x0 - mean) * rstd * gm.x + bt.x;
  o.y = (x1 - mean) * rstd * gm.y + bt.y;
  o.z = (x2 - mean) * rstd * gm.z + bt.z;
  o.w = (x3 - mean) * rstd * gm.w + bt.w;
  *(float4*)&out[baser + t * 4] = o;
  if (outb) {
    ushort4 ob;
    ob.x = f2bf(o.x); ob.y = f2bf(o.y); ob.z = f2bf(o.z); ob.w = f2bf(o.w);
    *(ushort4*)&outb[baser + t * 4] = ob;
  }
}

// ---------------------------------------------------------------------------
// ws (48MB): P1: 0-8 srcb | 8-14 WqkvT | 14 bqkv | 16-40 qkv | 40-48 vt.
// attn: Opart 0-16 (srcb/WqkvT dead). d_out: ls +8, maskb +8.5, WoT +9-11,
// ctxb 0-8. Wo-gemm -> mhsa ws 16-32. LN1 -> x1 fp32 = d_out 0-16
// (ctxb/ls/maskb/WoT dead), x1b ws 8-16. W1T ws 0-8 -> FFN1 -> hb ws 16-48.
// W2T ws 0-8 -> FFN2 K=4096 -> f2b ws 8-16 (x1b dead). LN2 -> d_out.
// ---------------------------------------------------------------------------
extern "C" void kernel_launch(void* const* d_in, const int* in_sizes, int n_in,
                              void* d_out, int out_size, void* d_ws, size_t ws_size,
                              hipStream_t stream) {
  const float* src  = (const float*)d_in[0];
  const int*   kmsk = (const int*)  d_in[1];
  const float* Wq   = (const float*)d_in[2];
  const float* bq   = (const float*)d_in[3];
  const float* Wk   = (const float*)d_in[4];
  const float* bk   = (const float*)d_in[5];
  const float* Wv   = (const float*)d_in[6];
  const float* bv   = (const float*)d_in[7];
  const float* Wo   = (const float*)d_in[8];
  const float* bo   = (const float*)d_in[9];
  const float* ln1g = (const float*)d_in[10];
  const float* ln1b = (const float*)d_in[11];
  const float* W1   = (const float*)d_in[12];
  const float* b1   = (const float*)d_in[13];
  const float* W2   = (const float*)d_in[14];
  const float* b2   = (const float*)d_in[15];
  const float* ln2g = (const float*)d_in[16];
  const float* ln2b = (const float*)d_in[17];

  char* w8 = (char*)d_ws;
  char* o8 = (char*)d_out;
  const size_t MB = 1024 * 1024;
  unsigned short* srcb  = (unsigned short*)(w8 + 0 * MB);
  unsigned short* WqkvT = (unsigned short*)(w8 + 8 * MB);
  float*          bqkv  = (float*)(w8 + 14 * MB);
  unsigned short* qkv   = (unsigned short*)(w8 + 16 * MB);
  unsigned short* vt    = (unsigned short*)(w8 + 40 * MB);
  unsigned short* Opart = (unsigned short*)(w8 + 0 * MB);   // 16 MB
  float*          ls    = (float*)(o8 + 8 * MB);            // 512 KB
  float*          maskb = (float*)(o8 + 8 * MB + 512 * 1024);  // 16 KB
  unsigned short* WoT   = (unsigned short*)(o8 + 9 * MB);   // 2 MB
  unsigned short* ctxb  = (unsigned short*)d_out;           // 8 MB
  float*          mhsa  = (float*)(w8 + 16 * MB);           // 16 MB
  float*          x1    = (float*)d_out;                    // 16 MB fp32
  unsigned short* x1b   = (unsigned short*)(w8 + 8 * MB);   // 8 MB
  unsigned short* W1T   = (unsigned short*)(w8 + 0 * MB);   // 8 MB full
  unsigned short* hb    = (unsigned short*)(w8 + 16 * MB);  // 32 MB full
  unsigned short* W2T   = (unsigned short*)(w8 + 0 * MB);   // 8 MB full
  unsigned short* f2b   = (unsigned short*)(w8 + 8 * MB);   // 8 MB

  dim3 blk(256);

  convert_bf16<<<ROWS * Hd / 1024 + 12 + 16, blk, 0, stream>>>(
      src, srcb, bq, bk, bv, bqkv, kmsk, maskb);
  convert_transpose4<<<dim3(16, 16, 4), blk, 0, stream>>>(
      Wq, Wk, Wv, Wo, WqkvT, WqkvT + 1024 * 1024, WqkvT + 2 * 1024 * 1024, WoT);

  // fused QKV: [4096][3072] = srcb @ WqkvT^T  (BK=64 single-buf, grid 24x32)
  gemm_bt<128, 0, 1, 0><<<dim3(QKVLD / 128, ROWS / 128), blk, 0, stream>>>(
      srcb, Hd, WqkvT, Hd, bqkv, qkv, QKVLD, Hd);

  transpose_v<<<1024, blk, 0, stream>>>(qkv + 2048, vt);
  attn_mfma<<<1024, blk, 0, stream>>>(qkv, qkv + 1024, vt, maskb, Opart, ls);
  attn_combine<<<ROWS, blk, 0, stream>>>(Opart, ls, ctxb);

  // Wo: grid-limited 2 blocks/CU -> DBUF hides DMA latency in-block
  gemm_bt<64, 0, 0, 1><<<dim3(Hd / 64, ROWS / 128), blk, 0, stream>>>(
      ctxb, Hd, WoT, Hd, bo, mhsa, Hd, Hd);

  add_ln_kernel<0><<<ROWS, blk, 0, stream>>>(mhsa, src, ln1g, ln1b, x1, x1b);

  // FFN single-pass: W1T [4096][1024], hb [4096][4096] bf16, W2T [1024][4096]
  convert_transpose<<<dim3(64, 16), blk, 0, stream>>>(W1, FFND, W1T, Hd);
  gemm_bt<128, 1, 1, 0><<<dim3(FFND / 128, ROWS / 128), blk, 0, stream>>>(
      x1b, Hd, W1T, Hd, b1, hb, FFND, Hd);
  convert_transpose<<<dim3(16, 64), blk, 0, stream>>>(W2, Hd, W2T, FFND);
  // FFN2: grid-limited 2 blocks/CU -> DBUF
  gemm_bt<64, 0, 1, 1><<<dim3(Hd / 64, ROWS / 128), blk, 0, stream>>>(
      hb, FFND, W2T, FFND, b2, f2b, Hd, FFND);

  add_ln_kernel<1><<<ROWS, blk, 0, stream>>>(f2b, x1, ln2g, ln2b,
                                             (float*)d_out, nullptr);
}